// Round 10
// baseline (1386.313 us; speedup 1.0000x reference)
//
#include <hip/hip_runtime.h>

#define K256 __launch_bounds__(256)

constexpr int B = 128;
constexpr int NM = 100000, EM = 400000;
constexpr int NP = 200000, EP = 3200000;
constexpr int DM = 78, DPK = 54, DP2 = 108;
constexpr int XH = 32;  // bf16 row stride in ushort2 units (64 bf16 = 128 B, line-aligned)

// ---- bf16 helpers (RTNE) ----
__device__ __forceinline__ float b2f(unsigned short u) {
  return __uint_as_float((unsigned int)u << 16);
}
__device__ __forceinline__ unsigned short f2b(float f) {
  unsigned int b = __float_as_uint(f);
  return (unsigned short)((b + 0x7fffu + ((b >> 16) & 1u)) >> 16);
}

// ---------- CSR build ----------
__global__ void K256 k_count4(const int4* __restrict__ dst, int* __restrict__ deg, int E4) {
  int e = blockIdx.x * 256 + threadIdx.x;
  if (e < E4) {
    int4 v = dst[e];
    atomicAdd(&deg[v.x], 1);
    atomicAdd(&deg[v.y], 1);
    atomicAdd(&deg[v.z], 1);
    atomicAdd(&deg[v.w], 1);
  }
}

__global__ void k_scan1(const int* __restrict__ deg, int* __restrict__ incl,
                        int* __restrict__ bsum, int N) {
  __shared__ int s[1024];
  int i = blockIdx.x * 1024 + threadIdx.x;
  int v = (i < N) ? deg[i] : 0;
  s[threadIdx.x] = v;
  __syncthreads();
  for (int off = 1; off < 1024; off <<= 1) {
    int t = (threadIdx.x >= off) ? s[threadIdx.x - off] : 0;
    __syncthreads();
    s[threadIdx.x] += t;
    __syncthreads();
  }
  if (i < N) incl[i] = s[threadIdx.x];
  if (threadIdx.x == 1023) bsum[blockIdx.x] = s[1023];
}

__global__ void k_scan2(int* __restrict__ bsum, int nb) {
  __shared__ int s[256];
  int v = (threadIdx.x < (unsigned)nb) ? bsum[threadIdx.x] : 0;
  s[threadIdx.x] = v;
  __syncthreads();
  for (int off = 1; off < 256; off <<= 1) {
    int t = (threadIdx.x >= off) ? s[threadIdx.x - off] : 0;
    __syncthreads();
    s[threadIdx.x] += t;
    __syncthreads();
  }
  if (threadIdx.x < (unsigned)nb) bsum[threadIdx.x] = s[threadIdx.x] - v;  // exclusive
}

__global__ void K256 k_scan3(const int* __restrict__ incl, const int* __restrict__ deg,
                             const int* __restrict__ bsum, int* __restrict__ starts, int N) {
  int i = blockIdx.x * 256 + threadIdx.x;
  if (i < N) starts[i] = incl[i] - deg[i] + bsum[i >> 10];
}

template <int SH>
__global__ void K256 k_bcur(const int* __restrict__ starts, int* __restrict__ bcur, int N) {
  int b = blockIdx.x * 256 + threadIdx.x;
  int NB = (N + (1 << SH) - 1) >> SH;
  if (b < NB) bcur[b] = starts[b << SH];
}

// Pass A: bucket-grouped edge binning (counting-sort per 4096-edge chunk).
template <int SH>
__global__ void K256 k_bin(const int* __restrict__ src, const int* __restrict__ dst,
                           int* __restrict__ bcur, int2* __restrict__ binned, int E) {
  __shared__ int lh[512];
  __shared__ int gbase[512];
  int c0 = blockIdx.x * 4096;
  int tid = threadIdx.x;
  for (int t = tid; t < 512; t += 256) lh[t] = 0;
  __syncthreads();
  int r[16], dcache[16];
#pragma unroll
  for (int k = 0; k < 16; k++) {
    int e = c0 + k * 256 + tid;
    if (e < E) {
      int d = dst[e];
      dcache[k] = d;
      r[k] = atomicAdd(&lh[d >> SH], 1);
    }
  }
  __syncthreads();
  for (int b = tid; b < 512; b += 256) {
    int c = lh[b];
    gbase[b] = c ? atomicAdd(&bcur[b], c) : 0;
  }
  __syncthreads();
#pragma unroll
  for (int k = 0; k < 16; k++) {
    int e = c0 + k * 256 + tid;
    if (e < E) {
      int d = dcache[k];
      binned[gbase[d >> SH] + r[k]] = make_int2(src[e], d);
    }
  }
}

// Pass B: per-bucket CSR fill; node cursors in LDS.
template <int SH>
__global__ void K256 k_fill2(const int2* __restrict__ binned, const int* __restrict__ starts,
                             int* __restrict__ csr, int N, int E) {
  __shared__ int lcur[1 << SH];
  int b = blockIdx.x;
  int base = b << SH;
  int nn = min(N - base, 1 << SH);
  int tid = threadIdx.x;
  for (int t = tid; t < nn; t += 256) lcur[t] = starts[base + t];
  __syncthreads();
  int r0 = starts[base];
  int r1 = (base + (1 << SH) >= N) ? E : starts[base + (1 << SH)];
  for (int e = r0 + tid; e < r1; e += 256) {
    int2 sd = binned[e];
    int p = atomicAdd(&lcur[sd.y - base], 1);
    csr[p] = sd.x;
  }
}

// ---------- batch segment starts (batch is sorted) ----------
__global__ void K256 k_bstart(const int* __restrict__ batch, int* __restrict__ bstart, int N) {
  int i = blockIdx.x * 256 + threadIdx.x;
  if (i < N) {
    int b = batch[i];
    int pb = (i == 0) ? -1 : batch[i - 1];
    for (int bb = pb + 1; bb <= b; bb++) bstart[bb] = i;
    if (i == N - 1)
      for (int bb = b + 1; bb <= B; bb++) bstart[bb] = N;
  }
}

__global__ void k_inv(const int* __restrict__ bstart, float* __restrict__ inv) {
  int b = threadIdx.x;
  if (b < B) inv[b] = 1.f / fmaxf((float)(bstart[b + 1] - bstart[b]), 1.f);
}

// ---------- small transpose: out[c*R + r] = in[r*C + c] ----------
__global__ void K256 k_trans(const float* __restrict__ in, float* __restrict__ out, int R, int C) {
  int i = blockIdx.x * 256 + threadIdx.x;
  if (i < R * C) {
    int r = i / C, c = i - r * C;
    out[c * R + r] = in[i];
  }
}

// ---------- weight prep: cat-form transposed weights ----------
__global__ void K256 k_prepw(const float* __restrict__ c1Wl, const float* __restrict__ c1Wr,
                             const float* __restrict__ c1bl, const float* __restrict__ c2Wl,
                             const float* __restrict__ c2Wr, float* __restrict__ w1cat,
                             float* __restrict__ bl1c, float* __restrict__ w2cat) {
  int i = blockIdx.x * 256 + threadIdx.x;
  if (i < 108 * 56) {
    int k = i / 56, o = i - k * 56;
    w1cat[i] = (o < 54) ? ((k < 54) ? c1Wl[o * 54 + k] : c1Wr[o * 54 + (k - 54)]) : 0.f;
  }
  if (i < 108 * 108) {
    int k = i / 108, o = i - k * 108;
    w2cat[i] = (k < 54) ? c2Wl[o * 54 + k] : c2Wr[o * 54 + (k - 54)];
  }
  if (i < 56) bl1c[i] = (i < 54) ? c1bl[i] : 0.f;
}

// ---------- cast pro_x (f32 stride 54) -> bf16 rows (stride XH ushort2) ----------
__global__ void K256 k_cast(const float* __restrict__ x, ushort2* __restrict__ xh, int N) {
  int t = blockIdx.x * 256 + threadIdx.x;
  if (t < N * 27) {
    int n = t / 27, j = t - n * 27;
    float2 v = *(const float2*)(x + (size_t)n * 54 + 2 * j);
    xh[(size_t)n * XH + j] = make_ushort2(f2b(v.x), f2b(v.y));
  }
}

// ---------- bf16 gather: wave per node, 27 active lanes/half, 4-deep edge ILP ----------
__global__ void K256 k_gatherh(const ushort2* __restrict__ xh, const int* __restrict__ starts,
                               const int* __restrict__ deg, const int* __restrict__ csr,
                               ushort2* __restrict__ outh, int N) {
  int wid = (blockIdx.x * 256 + threadIdx.x) >> 6;
  int lane = threadIdx.x & 63;
  if (wid >= N) return;
  int s = starts[wid], d = deg[wid];
  const int* cp = csr + s;
  int half = lane >> 5, sl = lane & 31;
  bool act = sl < 27;
  float ax = 0.f, ay = 0.f, bx = 0.f, by = 0.f;
  int j = 0;
  for (; j + 4 <= d; j += 4) {
    if (act) {
      ushort2 v0 = xh[(size_t)cp[j + half] * XH + sl];
      ushort2 v1 = xh[(size_t)cp[j + 2 + half] * XH + sl];
      ax += b2f(v0.x);
      ay += b2f(v0.y);
      bx += b2f(v1.x);
      by += b2f(v1.y);
    }
  }
  for (; j < d; j += 2) {
    int e = j + half;
    if (e < d && act) {
      ushort2 v = xh[(size_t)cp[e] * XH + sl];
      ax += b2f(v.x);
      ay += b2f(v.y);
    }
  }
  ax += bx;
  ay += by;
  ax += __shfl_xor(ax, 32, 64);
  ay += __shfl_xor(ay, 32, 64);
  if (half == 0 && act) {
    float inv = 1.f / fmaxf((float)d, 1.f);
    outh[(size_t)wid * XH + sl] = make_ushort2(f2b(ax * inv), f2b(ay * inv));
  }
}

// ---------- f32 gather (mol): wave per node, float2 lanes, 2-deep edge ILP ----------
template <int D, bool MEAN>
__global__ void K256 k_gatherv(const float* __restrict__ x, const int* __restrict__ starts,
                               const int* __restrict__ deg, const int* __restrict__ csr,
                               float* __restrict__ out, int N, int ostride) {
  constexpr int NF2 = D / 2;
  int wid = (blockIdx.x * 256 + threadIdx.x) >> 6;
  int lane = threadIdx.x & 63;
  if (wid >= N) return;
  int s = starts[wid], d = deg[wid];
  const int* cp = csr + s;
  float ax = 0.f, ay = 0.f;
  bool act = lane < NF2;
  float bx = 0.f, by = 0.f;
  int j = 0;
  for (; j + 2 <= d; j += 2) {
    if (act) {
      const float2* r0 = (const float2*)(x + (size_t)cp[j] * D);
      const float2* r1 = (const float2*)(x + (size_t)cp[j + 1] * D);
      float2 v0 = r0[lane];
      float2 v1 = r1[lane];
      ax += v0.x;
      ay += v0.y;
      bx += v1.x;
      by += v1.y;
    }
  }
  if (j < d && act) {
    const float2* row = (const float2*)(x + (size_t)cp[j] * D);
    float2 v = row[lane];
    ax += v.x;
    ay += v.y;
  }
  ax += bx;
  ay += by;
  if (act) {
    float inv = MEAN ? 1.f / fmaxf((float)d, 1.f) : 1.f;
    float2* op = (float2*)(out + (size_t)wid * ostride);
    float2 w;
    w.x = ax * inv;
    w.y = ay * inv;
    op[lane] = w;
  }
}

// ---------- segmented pooling ----------
template <int D, int NPB, bool ACCUM>
__global__ void K256 k_pool_seg(const float* __restrict__ x, const int* __restrict__ bstart,
                                float* __restrict__ pooled, float coef) {
  __shared__ float sp[D * NPB];
  int b = blockIdx.x, tid = threadIdx.x;
  int r0 = bstart[b], r1 = bstart[b + 1];
  if (tid < D * NPB) {
    int ioff = tid / D, f = tid - ioff * D;
    float acc = 0.f;
    for (int i = r0 + ioff; i < r1; i += NPB) acc += x[(size_t)i * D + f];
    sp[tid] = acc;
  }
  __syncthreads();
  if (tid < D) {
    float s = 0.f;
#pragma unroll
    for (int g = 0; g < NPB; g++) s += sp[g * D + tid];
    s *= coef;
    if (ACCUM)
      pooled[b * D + tid] += s;
    else
      pooled[b * D + tid] = s;
  }
}

// ---------- SAGE conv1 cat-form: 64-node tile, 4 waves x 14 outputs; bf16 agg in, bf16 out ----------
__global__ void __launch_bounds__(256, 4) k_sage1c(
    const float* __restrict__ x,        // pro_x f32, stride 54
    const ushort2* __restrict__ aggh,   // bf16, stride XH
    const float* __restrict__ wcat,     // [108][56]
    const float* __restrict__ blc,      // [56], pads 0
    ushort2* __restrict__ outh, int N) {  // bf16, stride XH
  __shared__ float scat[64 * 109];
  int base = blockIdx.x * 64;
  int nn = min(N - base, 64);
  int tid = threadIdx.x;
  for (int t = tid; t < nn * 27; t += 256) {
    int n = t / 27, j = t - n * 27;
    ushort2 va = aggh[(size_t)(base + n) * XH + j];
    float2 vx = *(const float2*)(x + (size_t)(base + n) * 54 + 2 * j);
    float* sr = scat + n * 109;
    sr[2 * j] = b2f(va.x);
    sr[2 * j + 1] = b2f(va.y);
    sr[54 + 2 * j] = vx.x;
    sr[54 + 2 * j + 1] = vx.y;
  }
  __syncthreads();
  int w = tid >> 6, lane = tid & 63;
  int obase = __builtin_amdgcn_readfirstlane(w * 14);
  if (lane >= nn) return;
  float acc[14];
#pragma unroll
  for (int o = 0; o < 14; o++) acc[o] = blc[obase + o];
  const float* rs = scat + lane * 109;
#pragma unroll 2
  for (int k = 0; k < 108; k++) {
    float v = rs[k];
    const float* wr = wcat + k * 56 + obase;
#pragma unroll
    for (int o = 0; o < 14; o++) acc[o] += v * wr[o];
  }
  ushort2* op = outh + (size_t)(base + lane) * XH + (obase >> 1);
#pragma unroll
  for (int o = 0; o < 7; o++)
    op[o] = make_ushort2(f2b(fmaxf(acc[2 * o], 0.f)), f2b(fmaxf(acc[2 * o + 1], 0.f)));
}

// ---------- conv2 + pool cat-form: 64-node tile, 4 waves x 27 outputs; bf16 inputs ----------
template <int SPLIT>
__global__ void __launch_bounds__(256, 4) k_sage2c(
    const ushort2* __restrict__ xt1h,   // bf16, stride XH
    const ushort2* __restrict__ aggh,   // bf16, stride XH
    const float* __restrict__ wcat,     // [108][108]
    const float* __restrict__ bl,       // [108]
    const int* __restrict__ bstart, float* __restrict__ pooled) {
  __shared__ float scat[64 * 109];
  int b = blockIdx.x / SPLIT;
  int sidx = blockIdx.x - b * SPLIT;
  int tid = threadIdx.x;
  int w = tid >> 6, lane = tid & 63;
  int obase = __builtin_amdgcn_readfirstlane(w * 27);
  int r0 = bstart[b], r1 = bstart[b + 1];
  int len = r1 - r0;
  int per = (len + SPLIT - 1) / SPLIT;
  int s0 = r0 + sidx * per;
  int s1 = min(r1, s0 + per);
  float pool[27];
#pragma unroll
  for (int o = 0; o < 27; o++) pool[o] = 0.f;
  for (int tb = s0; tb < s1; tb += 64) {
    int nn = min(s1 - tb, 64);
    __syncthreads();
    for (int t = tid; t < nn * 27; t += 256) {
      int n = t / 27, j = t - n * 27;
      ushort2 va = aggh[(size_t)(tb + n) * XH + j];
      ushort2 vx = xt1h[(size_t)(tb + n) * XH + j];
      float* sr = scat + n * 109;
      sr[2 * j] = b2f(va.x);
      sr[2 * j + 1] = b2f(va.y);
      sr[54 + 2 * j] = b2f(vx.x);
      sr[54 + 2 * j + 1] = b2f(vx.y);
    }
    __syncthreads();
    if (lane < nn) {
      float acc[27];
#pragma unroll
      for (int o = 0; o < 27; o++) acc[o] = bl[obase + o];
      const float* rs = scat + lane * 109;
#pragma unroll 2
      for (int k = 0; k < 108; k++) {
        float v = rs[k];
        const float* wr = wcat + k * 108 + obase;
#pragma unroll
        for (int o = 0; o < 27; o++) acc[o] += v * wr[o];
      }
#pragma unroll
      for (int o = 0; o < 27; o++) pool[o] += fmaxf(acc[o], 0.f);
    }
  }
#pragma unroll
  for (int o = 0; o < 27; o++) {
#pragma unroll
    for (int off = 1; off < 64; off <<= 1) pool[o] += __shfl_xor(pool[o], off, 64);
  }
  if (lane == 0) {
    float* pb = pooled + b * DP2 + obase;
#pragma unroll
    for (int o = 0; o < 27; o++)
      if (pool[o] != 0.f) atomicAdd(&pb[o], pool[o]);
  }
}

// ---------- tiny GEMM: Y[128][DOUT](+ycol0,stride) = act(X[128][DIN] (*rs) @ WT + b) ----------
// thread = one output col, 8 batch rows; WT[k][o] coalesced; X tile broadcast from LDS.
template <int DIN, int DOUT, bool RELU>
__global__ void K256 k_mlp(const float* __restrict__ X, int xstride,
                           const float* __restrict__ rs, const float* __restrict__ WT,
                           const float* __restrict__ bias, float* __restrict__ Y,
                           int ystride, int ycol0) {
  constexpr int BT = 8;
  __shared__ float Xs[BT][DIN];
  int tid = threadIdx.x;
  int ob = blockIdx.x * 256 + tid;
  int bb = blockIdx.y * BT;
  for (int t = tid; t < BT * DIN; t += 256) {
    int i = t / DIN, k = t - i * DIN;
    float v = X[(size_t)(bb + i) * xstride + k];
    if (rs) v *= rs[bb + i];
    Xs[i][k] = v;
  }
  __syncthreads();
  int o = (ob < DOUT) ? ob : (DOUT - 1);
  float bv = bias[o];
  float acc[BT];
#pragma unroll
  for (int i = 0; i < BT; i++) acc[i] = bv;
#pragma unroll 4
  for (int k = 0; k < DIN; k++) {
    float w = WT[(size_t)k * DOUT + o];
#pragma unroll
    for (int i = 0; i < BT; i++) acc[i] += Xs[i][k] * w;
  }
  if (ob < DOUT) {
#pragma unroll
    for (int i = 0; i < BT; i++) {
      float v = RELU ? fmaxf(acc[i], 0.f) : acc[i];
      Y[(size_t)(bb + i) * ystride + ycol0 + ob] = v;
    }
  }
}

// ---------- final 512 -> 1 GEMV: one wave per batch ----------
__global__ void __launch_bounds__(64) k_gemv1(const float* __restrict__ t2,
                                              const float* __restrict__ W3,
                                              const float* __restrict__ b3,
                                              float* __restrict__ out) {
  int b = blockIdx.x, lane = threadIdx.x;
  float a = 0.f;
  const float* row = t2 + (size_t)b * 512;
#pragma unroll 2
  for (int k = lane; k < 512; k += 64) a += row[k] * W3[k];
#pragma unroll
  for (int off = 32; off > 0; off >>= 1) a += __shfl_down(a, off, 64);
  if (lane == 0) out[b] = a + b3[0];
}

__global__ void k_report(float* out, float v, int n) {
  int i = blockIdx.x * 256 + threadIdx.x;
  if (i < n) out[i] = v;
}

extern "C" void kernel_launch(void* const* d_in, const int* in_sizes, int n_in,
                              void* d_out, int out_size, void* d_ws, size_t ws_size,
                              hipStream_t stream) {
  (void)in_sizes; (void)n_in;
  const float* mol_x = (const float*)d_in[0];
  const int* m_ei = (const int*)d_in[1];
  const int* m_batch = (const int*)d_in[2];
  const float* pro_x = (const float*)d_in[3];
  const int* p_ei = (const int*)d_in[4];
  const int* p_batch = (const int*)d_in[5];
  const float* mol_W1 = (const float*)d_in[6];
  const float* mol_b1 = (const float*)d_in[7];
  const float* mol_W2 = (const float*)d_in[8];
  const float* mol_b2 = (const float*)d_in[9];
  const float* c1_Wl = (const float*)d_in[10];
  const float* c1_bl = (const float*)d_in[11];
  const float* c1_Wr = (const float*)d_in[12];
  const float* c2_Wl = (const float*)d_in[13];
  const float* c2_bl = (const float*)d_in[14];
  const float* c2_Wr = (const float*)d_in[15];
  const float* pro_W1 = (const float*)d_in[16];
  const float* pro_b1 = (const float*)d_in[17];
  const float* pro_W2 = (const float*)d_in[18];
  const float* pro_b2 = (const float*)d_in[19];
  const float* fc1_W = (const float*)d_in[20];
  const float* fc1_b = (const float*)d_in[21];
  const float* fc2_W = (const float*)d_in[22];
  const float* fc2_b = (const float*)d_in[23];
  const float* out_W = (const float*)d_in[24];
  const float* out_b = (const float*)d_in[25];
  float* out = (float*)d_out;
  char* ws = (char*)d_ws;

  const int* m_row = m_ei;       // dst
  const int* m_col = m_ei + EM;  // src
  const int* p_e0 = p_ei;        // src
  const int* p_e1 = p_ei + EP;   // dst

  auto al = [](size_t x) { return (x + 255) & ~(size_t)255; };

  size_t o = 0;
  size_t o_pdeg = o;   o += al((size_t)NP * 4);
  size_t o_pincl = o;  o += al((size_t)NP * 4);
  size_t o_pstart = o; o += al((size_t)NP * 4);
  size_t o_pbsum = o;  o += al(1024);
  size_t o_pcsr = o;   o += al((size_t)EP * 4);
  size_t o_aggh = o;   o += al((size_t)NP * XH * 4);  // bf16 rows; also pro binned
  size_t o_xt1h = o;   o += al((size_t)NP * XH * 4);
  size_t o_pxh = o;    o += al((size_t)NP * XH * 4);
  size_t pro_end = o;

  o = 0;
  size_t o_mdeg = o;   o += al((size_t)NM * 4);
  size_t o_mincl = o;  o += al((size_t)NM * 4);
  size_t o_mstart = o; o += al((size_t)NM * 4);
  size_t o_mbsum = o;  o += al(1024);
  size_t o_mcsr = o;   o += al((size_t)EM * 4);
  size_t o_hA = o;     o += al((size_t)NM * DM * 4);  // also mol binned
  size_t o_hB = o;     o += al((size_t)NM * DM * 4);
  size_t mol_end = o;

  size_t tail = al(pro_end > mol_end ? pro_end : mol_end);
  size_t o_poolM = tail; tail += al((size_t)B * DM * 4);
  size_t o_poolP = tail; tail += al((size_t)B * DP2 * 4);
  size_t o_mbs = tail;   tail += al((size_t)(B + 1) * 4);
  size_t o_pbs = tail;   tail += al((size_t)(B + 1) * 4);
  size_t o_w1c = tail;   tail += al((size_t)108 * 56 * 4);
  size_t o_bl1 = tail;   tail += al(56 * 4);
  size_t o_w2c = tail;   tail += al((size_t)108 * 108 * 4);
  size_t o_mbc = tail;   tail += al(512 * 4);
  size_t o_pbc = tail;   tail += al(512 * 4);
  // MLP machinery
  size_t o_mh1T = tail;  tail += al((size_t)DM * 256 * 4);
  size_t o_mh2T = tail;  tail += al((size_t)256 * 112 * 4);
  size_t o_ph1T = tail;  tail += al((size_t)DP2 * 256 * 4);
  size_t o_ph2T = tail;  tail += al((size_t)256 * 144 * 4);
  size_t o_fc1T = tail;  tail += al((size_t)256 * 1024 * 4);
  size_t o_fc2T = tail;  tail += al((size_t)1024 * 512 * 4);
  size_t o_xc = tail;    tail += al((size_t)B * 256 * 4);
  size_t o_t1 = tail;    tail += al((size_t)B * 1024 * 4);
  size_t o_t2 = tail;    tail += al((size_t)B * 512 * 4);
  size_t o_th = tail;    tail += al((size_t)B * 256 * 4);
  size_t o_invM = tail;  tail += al(B * 4);
  size_t o_invP = tail;  tail += al(B * 4);

  if (ws_size < tail) {
    k_report<<<1, 256, 0, stream>>>(out, (float)(ws_size >> 20), out_size);
    return;
  }

  int* mdeg = (int*)(ws + o_mdeg);
  int* mincl = (int*)(ws + o_mincl);
  int* mstart = (int*)(ws + o_mstart);
  int* mbsum = (int*)(ws + o_mbsum);
  int* mcsr = (int*)(ws + o_mcsr);
  float* hA = (float*)(ws + o_hA);
  float* hB = (float*)(ws + o_hB);
  int* pdeg = (int*)(ws + o_pdeg);
  int* pincl = (int*)(ws + o_pincl);
  int* pstart = (int*)(ws + o_pstart);
  int* pbsum = (int*)(ws + o_pbsum);
  int* pcsr = (int*)(ws + o_pcsr);
  ushort2* aggh = (ushort2*)(ws + o_aggh);
  ushort2* xt1h = (ushort2*)(ws + o_xt1h);
  ushort2* pxh = (ushort2*)(ws + o_pxh);
  float* poolM = (float*)(ws + o_poolM);
  float* poolP = (float*)(ws + o_poolP);
  int* mbs = (int*)(ws + o_mbs);
  int* pbs = (int*)(ws + o_pbs);
  float* w1cat = (float*)(ws + o_w1c);
  float* bl1c = (float*)(ws + o_bl1);
  float* w2cat = (float*)(ws + o_w2c);
  int* mbc = (int*)(ws + o_mbc);
  int* pbc = (int*)(ws + o_pbc);
  float* mh1T = (float*)(ws + o_mh1T);
  float* mh2T = (float*)(ws + o_mh2T);
  float* ph1T = (float*)(ws + o_ph1T);
  float* ph2T = (float*)(ws + o_ph2T);
  float* fc1T = (float*)(ws + o_fc1T);
  float* fc2T = (float*)(ws + o_fc2T);
  float* xc = (float*)(ws + o_xc);
  float* t1 = (float*)(ws + o_t1);
  float* t2 = (float*)(ws + o_t2);
  float* th = (float*)(ws + o_th);
  float* invM = (float*)(ws + o_invM);
  float* invP = (float*)(ws + o_invP);
  int2* mbinned = (int2*)hA;
  int2* pbinned = (int2*)aggh;  // consumed by fill2 before aggh is written

  // weight prep (tiny, independent of graph work)
  k_prepw<<<(108 * 108 + 255) / 256, 256, 0, stream>>>(c1_Wl, c1_Wr, c1_bl, c2_Wl, c2_Wr,
                                                       w1cat, bl1c, w2cat);
  k_trans<<<(256 * DM + 255) / 256, 256, 0, stream>>>(mol_W1, mh1T, 256, DM);
  k_trans<<<(112 * 256 + 255) / 256, 256, 0, stream>>>(mol_W2, mh2T, 112, 256);
  k_trans<<<(256 * DP2 + 255) / 256, 256, 0, stream>>>(pro_W1, ph1T, 256, DP2);
  k_trans<<<(144 * 256 + 255) / 256, 256, 0, stream>>>(pro_W2, ph2T, 144, 256);
  k_trans<<<(1024 * 256 + 255) / 256, 256, 0, stream>>>(fc1_W, fc1T, 1024, 256);
  k_trans<<<(512 * 1024 + 255) / 256, 256, 0, stream>>>(fc2_W, fc2T, 512, 1024);

  // ===== MOL branch (f32 — APPNP amplifies magnitudes; keep exact) =====
  constexpr int SHM = 8;
  constexpr int NBM = (NM + (1 << SHM) - 1) >> SHM;
  hipMemsetAsync(mdeg, 0, (size_t)NM * 4, stream);
  k_count4<<<(EM / 4 + 255) / 256, 256, 0, stream>>>((const int4*)m_row, mdeg, EM / 4);
  int nb_m = (NM + 1023) / 1024;
  k_scan1<<<nb_m, 1024, 0, stream>>>(mdeg, mincl, mbsum, NM);
  k_scan2<<<1, 256, 0, stream>>>(mbsum, nb_m);
  k_scan3<<<(NM + 255) / 256, 256, 0, stream>>>(mincl, mdeg, mbsum, mstart, NM);
  k_bcur<SHM><<<(NBM + 255) / 256, 256, 0, stream>>>(mstart, mbc, NM);
  k_bin<SHM><<<(EM + 4095) / 4096, 256, 0, stream>>>(m_col, m_row, mbc, mbinned, EM);
  k_fill2<SHM><<<NBM, 256, 0, stream>>>(mbinned, mstart, mcsr, NM, EM);
  k_bstart<<<(NM + 255) / 256, 256, 0, stream>>>(m_batch, mbs, NM);
  k_inv<<<1, 128, 0, stream>>>(mbs, invM);

  int gb_m = (NM * 64 + 255) / 256;
  k_pool_seg<DM, 3, false><<<B, 256, 0, stream>>>(mol_x, mbs, poolM, 0.05f);
  k_gatherv<DM, false><<<gb_m, 256, 0, stream>>>(mol_x, mstart, mdeg, mcsr, hA, NM, DM);
  k_pool_seg<DM, 3, true><<<B, 256, 0, stream>>>(hA, mbs, poolM, 0.2375f);
  k_gatherv<DM, false><<<gb_m, 256, 0, stream>>>(hA, mstart, mdeg, mcsr, hB, NM, DM);
  k_pool_seg<DM, 3, true><<<B, 256, 0, stream>>>(hB, mbs, poolM, 0.2375f);
  k_gatherv<DM, false><<<gb_m, 256, 0, stream>>>(hB, mstart, mdeg, mcsr, hA, NM, DM);
  k_pool_seg<DM, 3, true><<<B, 256, 0, stream>>>(hA, mbs, poolM, 0.2375f);
  k_gatherv<DM, false><<<gb_m, 256, 0, stream>>>(hA, mstart, mdeg, mcsr, hB, NM, DM);
  k_pool_seg<DM, 3, true><<<B, 256, 0, stream>>>(hB, mbs, poolM, 0.2375f);
  // mol head: poolM/cnt -> 256 relu -> xc[:, 0:112]
  {
    dim3 g1(1, B / 8);
    k_mlp<DM, 256, true><<<g1, 256, 0, stream>>>(poolM, DM, invM, mh1T, mol_b1, th, 256, 0);
    k_mlp<256, 112, false><<<g1, 256, 0, stream>>>(th, 256, nullptr, mh2T, mol_b2, xc, 256, 0);
  }

  // ===== PRO branch (bf16 feature rows; mean-aggr keeps noise bounded) =====
  constexpr int SHP = 9;
  constexpr int NBP = (NP + (1 << SHP) - 1) >> SHP;
  hipMemsetAsync(pdeg, 0, (size_t)NP * 4, stream);
  hipMemsetAsync(poolP, 0, (size_t)B * DP2 * 4, stream);
  k_count4<<<(EP / 4 + 255) / 256, 256, 0, stream>>>((const int4*)p_e1, pdeg, EP / 4);
  int nb_p = (NP + 1023) / 1024;
  k_scan1<<<nb_p, 1024, 0, stream>>>(pdeg, pincl, pbsum, NP);
  k_scan2<<<1, 256, 0, stream>>>(pbsum, nb_p);
  k_scan3<<<(NP + 255) / 256, 256, 0, stream>>>(pincl, pdeg, pbsum, pstart, NP);
  k_bcur<SHP><<<(NBP + 255) / 256, 256, 0, stream>>>(pstart, pbc, NP);
  k_bin<SHP><<<(EP + 4095) / 4096, 256, 0, stream>>>(p_e0, p_e1, pbc, pbinned, EP);
  k_fill2<SHP><<<NBP, 256, 0, stream>>>(pbinned, pstart, pcsr, NP, EP);
  k_bstart<<<(NP + 255) / 256, 256, 0, stream>>>(p_batch, pbs, NP);
  k_inv<<<1, 128, 0, stream>>>(pbs, invP);
  k_cast<<<(NP * 27 + 255) / 256, 256, 0, stream>>>(pro_x, pxh, NP);

  int gb_p = (NP * 64 + 255) / 256;
  k_gatherh<<<gb_p, 256, 0, stream>>>(pxh, pstart, pdeg, pcsr, aggh, NP);
  k_sage1c<<<(NP + 63) / 64, 256, 0, stream>>>(pro_x, aggh, w1cat, bl1c, xt1h, NP);
  k_gatherh<<<gb_p, 256, 0, stream>>>(xt1h, pstart, pdeg, pcsr, aggh, NP);
  k_sage2c<8><<<B * 8, 256, 0, stream>>>(xt1h, aggh, w2cat, c2_bl, pbs, poolP);
  // pro head: poolP/cnt -> 256 relu -> xc[:, 112:256]
  {
    dim3 g1(1, B / 8);
    k_mlp<DP2, 256, true><<<g1, 256, 0, stream>>>(poolP, DP2, invP, ph1T, pro_b1, th, 256, 0);
    k_mlp<256, 144, false><<<g1, 256, 0, stream>>>(th, 256, nullptr, ph2T, pro_b2, xc, 256, 112);
  }

  // ===== final MLP: xc -> 1024 relu -> 512 relu -> 1 =====
  {
    dim3 gA(4, B / 8);
    k_mlp<256, 1024, true><<<gA, 256, 0, stream>>>(xc, 256, nullptr, fc1T, fc1_b, t1, 1024, 0);
    dim3 gB(2, B / 8);
    k_mlp<1024, 512, true><<<gB, 256, 0, stream>>>(t1, 1024, nullptr, fc2T, fc2_b, t2, 512, 0);
    k_gemv1<<<B, 64, 0, stream>>>(t2, out_W, out_b, out);
  }
}

// Round 11
// 1264.157 us; speedup vs baseline: 1.0966x; 1.0966x over previous
//
#include <hip/hip_runtime.h>

#define K256 __launch_bounds__(256)

constexpr int B = 128;
constexpr int NM = 100000, EM = 400000;
constexpr int NP = 200000, EP = 3200000;
constexpr int DM = 78, DPK = 54, DP2 = 108;
constexpr int XH = 32;  // bf16 row stride in ushort2 units (64 bf16 = 128 B, line-aligned)

// ---- bf16 helpers (RTNE) ----
__device__ __forceinline__ float b2f(unsigned short u) {
  return __uint_as_float((unsigned int)u << 16);
}
__device__ __forceinline__ unsigned short f2b(float f) {
  unsigned int b = __float_as_uint(f);
  return (unsigned short)((b + 0x7fffu + ((b >> 16) & 1u)) >> 16);
}

// ---------- CSR build: bucket histogram (LDS-aggregated, no per-node atomics) ----------
template <int SH>
__global__ void K256 k_bhist(const int* __restrict__ dst, int* __restrict__ bhist, int E) {
  __shared__ int lh[512];
  int tid = threadIdx.x;
  for (int t = tid; t < 512; t += 256) lh[t] = 0;
  __syncthreads();
  int c0 = blockIdx.x * 4096;
#pragma unroll
  for (int k = 0; k < 16; k++) {
    int e = c0 + k * 256 + tid;
    if (e < E) atomicAdd(&lh[dst[e] >> SH], 1);
  }
  __syncthreads();
  for (int t = tid; t < 512; t += 256) {
    int c = lh[t];
    if (c) atomicAdd(&bhist[t], c);
  }
}

// one-block scan of bucket counts -> bed (exclusive, +total) and bcur
__global__ void k_scanb(const int* __restrict__ bhist, int* __restrict__ bed,
                        int* __restrict__ bcur, int NB, int E) {
  __shared__ int s[512];
  int tid = threadIdx.x;
  int v = (tid < NB) ? bhist[tid] : 0;
  s[tid] = v;
  __syncthreads();
  for (int off = 1; off < 512; off <<= 1) {
    int t = (tid >= off) ? s[tid - off] : 0;
    __syncthreads();
    s[tid] += t;
    __syncthreads();
  }
  int excl = s[tid] - v;
  if (tid < NB) {
    bed[tid] = excl;
    bcur[tid] = excl;
  }
  if (tid == NB - 1) bed[NB] = E;
}

// Pass A: bucket-grouped edge binning (counting-sort per 4096-edge chunk).
template <int SH>
__global__ void K256 k_bin(const int* __restrict__ src, const int* __restrict__ dst,
                           int* __restrict__ bcur, int2* __restrict__ binned, int E) {
  __shared__ int lh[512];
  __shared__ int gbase[512];
  int c0 = blockIdx.x * 4096;
  int tid = threadIdx.x;
  for (int t = tid; t < 512; t += 256) lh[t] = 0;
  __syncthreads();
  int r[16], dcache[16];
#pragma unroll
  for (int k = 0; k < 16; k++) {
    int e = c0 + k * 256 + tid;
    if (e < E) {
      int d = dst[e];
      dcache[k] = d;
      r[k] = atomicAdd(&lh[d >> SH], 1);
    }
  }
  __syncthreads();
  for (int b = tid; b < 512; b += 256) {
    int c = lh[b];
    gbase[b] = c ? atomicAdd(&bcur[b], c) : 0;
  }
  __syncthreads();
#pragma unroll
  for (int k = 0; k < 16; k++) {
    int e = c0 + k * 256 + tid;
    if (e < E) {
      int d = dcache[k];
      binned[gbase[d >> SH] + r[k]] = make_int2(src[e], d);
    }
  }
}

// Pass B (fused): per-bucket count -> LDS scan -> deg/starts write -> CSR fill.
template <int SH>
__global__ void K256 k_build(const int2* __restrict__ binned, const int* __restrict__ bed,
                             int* __restrict__ deg, int* __restrict__ starts,
                             int* __restrict__ csr, int N) {
  constexpr int NN = 1 << SH;
  constexpr int P = NN / 256;
  __shared__ int lcnt[NN];
  __shared__ int lpair[256];
  int b = blockIdx.x, base = b << SH, tid = threadIdx.x;
  int nn = min(N - base, NN);
  for (int t = tid; t < NN; t += 256) lcnt[t] = 0;
  __syncthreads();
  int e0 = bed[b], e1 = bed[b + 1];
  for (int e = e0 + tid; e < e1; e += 256) atomicAdd(&lcnt[binned[e].y - base], 1);
  __syncthreads();
  int loc[P];
  int psum = 0;
#pragma unroll
  for (int p = 0; p < P; p++) {
    loc[p] = lcnt[tid * P + p];
    psum += loc[p];
  }
  lpair[tid] = psum;
  __syncthreads();
  for (int off = 1; off < 256; off <<= 1) {
    int t = (tid >= off) ? lpair[tid - off] : 0;
    __syncthreads();
    lpair[tid] += t;
    __syncthreads();
  }
  int run = lpair[tid] - psum;
  __syncthreads();  // done reading lcnt as counts; reuse as cursors
#pragma unroll
  for (int p = 0; p < P; p++) {
    int i = tid * P + p;
    int st = e0 + run;
    if (i < nn) {
      deg[base + i] = loc[p];
      starts[base + i] = st;
    }
    lcnt[i] = st;
    run += loc[p];
  }
  __syncthreads();
  for (int e = e0 + tid; e < e1; e += 256) {
    int2 sd = binned[e];
    int p = atomicAdd(&lcnt[sd.y - base], 1);
    csr[p] = sd.x;
  }
}

// ---------- batch segment starts (batch is sorted) ----------
__global__ void K256 k_bstart(const int* __restrict__ batch, int* __restrict__ bstart, int N) {
  int i = blockIdx.x * 256 + threadIdx.x;
  if (i < N) {
    int b = batch[i];
    int pb = (i == 0) ? -1 : batch[i - 1];
    for (int bb = pb + 1; bb <= b; bb++) bstart[bb] = i;
    if (i == N - 1)
      for (int bb = b + 1; bb <= B; bb++) bstart[bb] = N;
  }
}

__global__ void k_inv(const int* __restrict__ bstart, float* __restrict__ inv) {
  int b = threadIdx.x;
  if (b < B) inv[b] = 1.f / fmaxf((float)(bstart[b + 1] - bstart[b]), 1.f);
}

// ---------- tiled transpose: out[c*R + r] = in[r*C + c], coalesced both sides ----------
__global__ void K256 k_transT(const float* __restrict__ in, float* __restrict__ out, int R,
                              int C) {
  __shared__ float t[32][33];
  int cb = blockIdx.x * 32, rb = blockIdx.y * 32;
  int tx = threadIdx.x & 31, ty = threadIdx.x >> 5;
  for (int i = ty; i < 32; i += 8) {
    int r = rb + i, c = cb + tx;
    if (r < R && c < C) t[i][tx] = in[(size_t)r * C + c];
  }
  __syncthreads();
  for (int i = ty; i < 32; i += 8) {
    int c = cb + i, r = rb + tx;
    if (r < R && c < C) out[(size_t)c * R + r] = t[tx][i];
  }
}

// ---------- weight prep: cat-form transposed weights ----------
__global__ void K256 k_prepw(const float* __restrict__ c1Wl, const float* __restrict__ c1Wr,
                             const float* __restrict__ c1bl, const float* __restrict__ c2Wl,
                             const float* __restrict__ c2Wr, float* __restrict__ w1cat,
                             float* __restrict__ bl1c, float* __restrict__ w2cat) {
  int i = blockIdx.x * 256 + threadIdx.x;
  if (i < 108 * 56) {
    int k = i / 56, o = i - k * 56;
    w1cat[i] = (o < 54) ? ((k < 54) ? c1Wl[o * 54 + k] : c1Wr[o * 54 + (k - 54)]) : 0.f;
  }
  if (i < 108 * 108) {
    int k = i / 108, o = i - k * 108;
    w2cat[i] = (k < 54) ? c2Wl[o * 54 + k] : c2Wr[o * 54 + (k - 54)];
  }
  if (i < 56) bl1c[i] = (i < 54) ? c1bl[i] : 0.f;
}

// ---------- cast pro_x (f32 stride 54) -> bf16 rows (stride XH ushort2) ----------
__global__ void K256 k_cast(const float* __restrict__ x, ushort2* __restrict__ xh, int N) {
  int t = blockIdx.x * 256 + threadIdx.x;
  if (t < N * 27) {
    int n = t / 27, j = t - n * 27;
    float2 v = *(const float2*)(x + (size_t)n * 54 + 2 * j);
    xh[(size_t)n * XH + j] = make_ushort2(f2b(v.x), f2b(v.y));
  }
}

// ---------- bf16 gather: wave per node, 27 active lanes/half, 4-deep edge ILP ----------
__global__ void K256 k_gatherh(const ushort2* __restrict__ xh, const int* __restrict__ starts,
                               const int* __restrict__ deg, const int* __restrict__ csr,
                               ushort2* __restrict__ outh, int N) {
  int wid = (blockIdx.x * 256 + threadIdx.x) >> 6;
  int lane = threadIdx.x & 63;
  if (wid >= N) return;
  int s = starts[wid], d = deg[wid];
  const int* cp = csr + s;
  int half = lane >> 5, sl = lane & 31;
  bool act = sl < 27;
  float ax = 0.f, ay = 0.f, bx = 0.f, by = 0.f;
  int j = 0;
  for (; j + 4 <= d; j += 4) {
    if (act) {
      ushort2 v0 = xh[(size_t)cp[j + half] * XH + sl];
      ushort2 v1 = xh[(size_t)cp[j + 2 + half] * XH + sl];
      ax += b2f(v0.x);
      ay += b2f(v0.y);
      bx += b2f(v1.x);
      by += b2f(v1.y);
    }
  }
  for (; j < d; j += 2) {
    int e = j + half;
    if (e < d && act) {
      ushort2 v = xh[(size_t)cp[e] * XH + sl];
      ax += b2f(v.x);
      ay += b2f(v.y);
    }
  }
  ax += bx;
  ay += by;
  ax += __shfl_xor(ax, 32, 64);
  ay += __shfl_xor(ay, 32, 64);
  if (half == 0 && act) {
    float inv = 1.f / fmaxf((float)d, 1.f);
    outh[(size_t)wid * XH + sl] = make_ushort2(f2b(ax * inv), f2b(ay * inv));
  }
}

// ---------- f32 gather (mol): wave per node, float2 lanes, 2-deep edge ILP ----------
template <int D, bool MEAN>
__global__ void K256 k_gatherv(const float* __restrict__ x, const int* __restrict__ starts,
                               const int* __restrict__ deg, const int* __restrict__ csr,
                               float* __restrict__ out, int N, int ostride) {
  constexpr int NF2 = D / 2;
  int wid = (blockIdx.x * 256 + threadIdx.x) >> 6;
  int lane = threadIdx.x & 63;
  if (wid >= N) return;
  int s = starts[wid], d = deg[wid];
  const int* cp = csr + s;
  float ax = 0.f, ay = 0.f;
  bool act = lane < NF2;
  float bx = 0.f, by = 0.f;
  int j = 0;
  for (; j + 2 <= d; j += 2) {
    if (act) {
      const float2* r0 = (const float2*)(x + (size_t)cp[j] * D);
      const float2* r1 = (const float2*)(x + (size_t)cp[j + 1] * D);
      float2 v0 = r0[lane];
      float2 v1 = r1[lane];
      ax += v0.x;
      ay += v0.y;
      bx += v1.x;
      by += v1.y;
    }
  }
  if (j < d && act) {
    const float2* row = (const float2*)(x + (size_t)cp[j] * D);
    float2 v = row[lane];
    ax += v.x;
    ay += v.y;
  }
  ax += bx;
  ay += by;
  if (act) {
    float inv = MEAN ? 1.f / fmaxf((float)d, 1.f) : 1.f;
    float2* op = (float2*)(out + (size_t)wid * ostride);
    float2 w;
    w.x = ax * inv;
    w.y = ay * inv;
    op[lane] = w;
  }
}

// ---------- segmented pooling ----------
template <int D, int NPB, bool ACCUM>
__global__ void K256 k_pool_seg(const float* __restrict__ x, const int* __restrict__ bstart,
                                float* __restrict__ pooled, float coef) {
  __shared__ float sp[D * NPB];
  int b = blockIdx.x, tid = threadIdx.x;
  int r0 = bstart[b], r1 = bstart[b + 1];
  if (tid < D * NPB) {
    int ioff = tid / D, f = tid - ioff * D;
    float acc = 0.f;
    for (int i = r0 + ioff; i < r1; i += NPB) acc += x[(size_t)i * D + f];
    sp[tid] = acc;
  }
  __syncthreads();
  if (tid < D) {
    float s = 0.f;
#pragma unroll
    for (int g = 0; g < NPB; g++) s += sp[g * D + tid];
    s *= coef;
    if (ACCUM)
      pooled[b * D + tid] += s;
    else
      pooled[b * D + tid] = s;
  }
}

// ---------- SAGE conv1 cat-form: 64-node tile, 4 waves x 14 outputs; bf16 agg in, bf16 out ----------
__global__ void __launch_bounds__(256, 4) k_sage1c(
    const float* __restrict__ x, const ushort2* __restrict__ aggh,
    const float* __restrict__ wcat, const float* __restrict__ blc,
    ushort2* __restrict__ outh, int N) {
  __shared__ float scat[64 * 109];
  int base = blockIdx.x * 64;
  int nn = min(N - base, 64);
  int tid = threadIdx.x;
  for (int t = tid; t < nn * 27; t += 256) {
    int n = t / 27, j = t - n * 27;
    ushort2 va = aggh[(size_t)(base + n) * XH + j];
    float2 vx = *(const float2*)(x + (size_t)(base + n) * 54 + 2 * j);
    float* sr = scat + n * 109;
    sr[2 * j] = b2f(va.x);
    sr[2 * j + 1] = b2f(va.y);
    sr[54 + 2 * j] = vx.x;
    sr[54 + 2 * j + 1] = vx.y;
  }
  __syncthreads();
  int w = tid >> 6, lane = tid & 63;
  int obase = __builtin_amdgcn_readfirstlane(w * 14);
  if (lane >= nn) return;
  float acc[14];
#pragma unroll
  for (int o = 0; o < 14; o++) acc[o] = blc[obase + o];
  const float* rs = scat + lane * 109;
#pragma unroll 2
  for (int k = 0; k < 108; k++) {
    float v = rs[k];
    const float* wr = wcat + k * 56 + obase;
#pragma unroll
    for (int o = 0; o < 14; o++) acc[o] += v * wr[o];
  }
  ushort2* op = outh + (size_t)(base + lane) * XH + (obase >> 1);
#pragma unroll
  for (int o = 0; o < 7; o++)
    op[o] = make_ushort2(f2b(fmaxf(acc[2 * o], 0.f)), f2b(fmaxf(acc[2 * o + 1], 0.f)));
}

// ---------- conv2 + pool cat-form: 64-node tile, 4 waves x 27 outputs; bf16 inputs ----------
template <int SPLIT>
__global__ void __launch_bounds__(256, 4) k_sage2c(
    const ushort2* __restrict__ xt1h, const ushort2* __restrict__ aggh,
    const float* __restrict__ wcat, const float* __restrict__ bl,
    const int* __restrict__ bstart, float* __restrict__ pooled) {
  __shared__ float scat[64 * 109];
  int b = blockIdx.x / SPLIT;
  int sidx = blockIdx.x - b * SPLIT;
  int tid = threadIdx.x;
  int w = tid >> 6, lane = tid & 63;
  int obase = __builtin_amdgcn_readfirstlane(w * 27);
  int r0 = bstart[b], r1 = bstart[b + 1];
  int len = r1 - r0;
  int per = (len + SPLIT - 1) / SPLIT;
  int s0 = r0 + sidx * per;
  int s1 = min(r1, s0 + per);
  float pool[27];
#pragma unroll
  for (int o = 0; o < 27; o++) pool[o] = 0.f;
  for (int tb = s0; tb < s1; tb += 64) {
    int nn = min(s1 - tb, 64);
    __syncthreads();
    for (int t = tid; t < nn * 27; t += 256) {
      int n = t / 27, j = t - n * 27;
      ushort2 va = aggh[(size_t)(tb + n) * XH + j];
      ushort2 vx = xt1h[(size_t)(tb + n) * XH + j];
      float* sr = scat + n * 109;
      sr[2 * j] = b2f(va.x);
      sr[2 * j + 1] = b2f(va.y);
      sr[54 + 2 * j] = b2f(vx.x);
      sr[54 + 2 * j + 1] = b2f(vx.y);
    }
    __syncthreads();
    if (lane < nn) {
      float acc[27];
#pragma unroll
      for (int o = 0; o < 27; o++) acc[o] = bl[obase + o];
      const float* rs = scat + lane * 109;
#pragma unroll 2
      for (int k = 0; k < 108; k++) {
        float v = rs[k];
        const float* wr = wcat + k * 108 + obase;
#pragma unroll
        for (int o = 0; o < 27; o++) acc[o] += v * wr[o];
      }
#pragma unroll
      for (int o = 0; o < 27; o++) pool[o] += fmaxf(acc[o], 0.f);
    }
  }
#pragma unroll
  for (int o = 0; o < 27; o++) {
#pragma unroll
    for (int off = 1; off < 64; off <<= 1) pool[o] += __shfl_xor(pool[o], off, 64);
  }
  if (lane == 0) {
    float* pb = pooled + b * DP2 + obase;
#pragma unroll
    for (int o = 0; o < 27; o++)
      if (pool[o] != 0.f) atomicAdd(&pb[o], pool[o]);
  }
}

// ---------- tiny GEMM: Y[128][DOUT](+ycol0) = act(X[128][DIN] (*rs) @ WT + b) ----------
template <int DIN, int DOUT, bool RELU>
__global__ void K256 k_mlp(const float* __restrict__ X, int xstride,
                           const float* __restrict__ rs, const float* __restrict__ WT,
                           const float* __restrict__ bias, float* __restrict__ Y,
                           int ystride, int ycol0) {
  constexpr int BT = 8;
  __shared__ float Xs[BT][DIN];
  int tid = threadIdx.x;
  int ob = blockIdx.x * 256 + tid;
  int bb = blockIdx.y * BT;
  for (int t = tid; t < BT * DIN; t += 256) {
    int i = t / DIN, k = t - i * DIN;
    float v = X[(size_t)(bb + i) * xstride + k];
    if (rs) v *= rs[bb + i];
    Xs[i][k] = v;
  }
  __syncthreads();
  int o = (ob < DOUT) ? ob : (DOUT - 1);
  float bv = bias[o];
  float acc[BT];
#pragma unroll
  for (int i = 0; i < BT; i++) acc[i] = bv;
#pragma unroll 4
  for (int k = 0; k < DIN; k++) {
    float w = WT[(size_t)k * DOUT + o];
#pragma unroll
    for (int i = 0; i < BT; i++) acc[i] += Xs[i][k] * w;
  }
  if (ob < DOUT) {
#pragma unroll
    for (int i = 0; i < BT; i++) {
      float v = RELU ? fmaxf(acc[i], 0.f) : acc[i];
      Y[(size_t)(bb + i) * ystride + ycol0 + ob] = v;
    }
  }
}

// ---------- final 512 -> 1 GEMV: one wave per batch ----------
__global__ void __launch_bounds__(64) k_gemv1(const float* __restrict__ t2,
                                              const float* __restrict__ W3,
                                              const float* __restrict__ b3,
                                              float* __restrict__ out) {
  int b = blockIdx.x, lane = threadIdx.x;
  float a = 0.f;
  const float* row = t2 + (size_t)b * 512;
#pragma unroll 2
  for (int k = lane; k < 512; k += 64) a += row[k] * W3[k];
#pragma unroll
  for (int off = 32; off > 0; off >>= 1) a += __shfl_down(a, off, 64);
  if (lane == 0) out[b] = a + b3[0];
}

__global__ void k_report(float* out, float v, int n) {
  int i = blockIdx.x * 256 + threadIdx.x;
  if (i < n) out[i] = v;
}

extern "C" void kernel_launch(void* const* d_in, const int* in_sizes, int n_in,
                              void* d_out, int out_size, void* d_ws, size_t ws_size,
                              hipStream_t stream) {
  (void)in_sizes; (void)n_in;
  const float* mol_x = (const float*)d_in[0];
  const int* m_ei = (const int*)d_in[1];
  const int* m_batch = (const int*)d_in[2];
  const float* pro_x = (const float*)d_in[3];
  const int* p_ei = (const int*)d_in[4];
  const int* p_batch = (const int*)d_in[5];
  const float* mol_W1 = (const float*)d_in[6];
  const float* mol_b1 = (const float*)d_in[7];
  const float* mol_W2 = (const float*)d_in[8];
  const float* mol_b2 = (const float*)d_in[9];
  const float* c1_Wl = (const float*)d_in[10];
  const float* c1_bl = (const float*)d_in[11];
  const float* c1_Wr = (const float*)d_in[12];
  const float* c2_Wl = (const float*)d_in[13];
  const float* c2_bl = (const float*)d_in[14];
  const float* c2_Wr = (const float*)d_in[15];
  const float* pro_W1 = (const float*)d_in[16];
  const float* pro_b1 = (const float*)d_in[17];
  const float* pro_W2 = (const float*)d_in[18];
  const float* pro_b2 = (const float*)d_in[19];
  const float* fc1_W = (const float*)d_in[20];
  const float* fc1_b = (const float*)d_in[21];
  const float* fc2_W = (const float*)d_in[22];
  const float* fc2_b = (const float*)d_in[23];
  const float* out_W = (const float*)d_in[24];
  const float* out_b = (const float*)d_in[25];
  float* out = (float*)d_out;
  char* ws = (char*)d_ws;

  const int* m_row = m_ei;       // dst
  const int* m_col = m_ei + EM;  // src
  const int* p_e0 = p_ei;        // src
  const int* p_e1 = p_ei + EP;   // dst

  auto al = [](size_t x) { return (x + 255) & ~(size_t)255; };

  size_t o = 0;
  size_t o_pdeg = o;   o += al((size_t)NP * 4);
  size_t o_pstart = o; o += al((size_t)NP * 4);
  size_t o_pcsr = o;   o += al((size_t)EP * 4);
  size_t o_aggh = o;   o += al((size_t)NP * XH * 4);  // bf16 rows; also pro binned
  size_t o_xt1h = o;   o += al((size_t)NP * XH * 4);
  size_t o_pxh = o;    o += al((size_t)NP * XH * 4);
  size_t pro_end = o;

  o = 0;
  size_t o_mdeg = o;   o += al((size_t)NM * 4);
  size_t o_mstart = o; o += al((size_t)NM * 4);
  size_t o_mcsr = o;   o += al((size_t)EM * 4);
  size_t o_hA = o;     o += al((size_t)NM * DM * 4);  // also mol binned
  size_t o_hB = o;     o += al((size_t)NM * DM * 4);
  size_t mol_end = o;

  size_t tail = al(pro_end > mol_end ? pro_end : mol_end);
  size_t o_poolM = tail; tail += al((size_t)B * DM * 4);
  size_t o_poolP = tail; tail += al((size_t)B * DP2 * 4);
  size_t o_mbs = tail;   tail += al((size_t)(B + 1) * 4);
  size_t o_pbs = tail;   tail += al((size_t)(B + 1) * 4);
  size_t o_w1c = tail;   tail += al((size_t)108 * 56 * 4);
  size_t o_bl1 = tail;   tail += al(56 * 4);
  size_t o_w2c = tail;   tail += al((size_t)108 * 108 * 4);
  size_t o_mbc = tail;   tail += al(512 * 4);
  size_t o_pbc = tail;   tail += al(512 * 4);
  size_t o_mbh = tail;   tail += al(512 * 4);
  size_t o_pbh = tail;   tail += al(512 * 4);
  size_t o_mbed = tail;  tail += al(513 * 4);
  size_t o_pbed = tail;  tail += al(513 * 4);
  // MLP machinery
  size_t o_mh1T = tail;  tail += al((size_t)DM * 256 * 4);
  size_t o_mh2T = tail;  tail += al((size_t)256 * 112 * 4);
  size_t o_ph1T = tail;  tail += al((size_t)DP2 * 256 * 4);
  size_t o_ph2T = tail;  tail += al((size_t)256 * 144 * 4);
  size_t o_fc1T = tail;  tail += al((size_t)256 * 1024 * 4);
  size_t o_fc2T = tail;  tail += al((size_t)1024 * 512 * 4);
  size_t o_xc = tail;    tail += al((size_t)B * 256 * 4);
  size_t o_t1 = tail;    tail += al((size_t)B * 1024 * 4);
  size_t o_t2 = tail;    tail += al((size_t)B * 512 * 4);
  size_t o_th = tail;    tail += al((size_t)B * 256 * 4);
  size_t o_invM = tail;  tail += al(B * 4);
  size_t o_invP = tail;  tail += al(B * 4);

  if (ws_size < tail) {
    k_report<<<1, 256, 0, stream>>>(out, (float)(ws_size >> 20), out_size);
    return;
  }

  int* mdeg = (int*)(ws + o_mdeg);
  int* mstart = (int*)(ws + o_mstart);
  int* mcsr = (int*)(ws + o_mcsr);
  float* hA = (float*)(ws + o_hA);
  float* hB = (float*)(ws + o_hB);
  int* pdeg = (int*)(ws + o_pdeg);
  int* pstart = (int*)(ws + o_pstart);
  int* pcsr = (int*)(ws + o_pcsr);
  ushort2* aggh = (ushort2*)(ws + o_aggh);
  ushort2* xt1h = (ushort2*)(ws + o_xt1h);
  ushort2* pxh = (ushort2*)(ws + o_pxh);
  float* poolM = (float*)(ws + o_poolM);
  float* poolP = (float*)(ws + o_poolP);
  int* mbs = (int*)(ws + o_mbs);
  int* pbs = (int*)(ws + o_pbs);
  float* w1cat = (float*)(ws + o_w1c);
  float* bl1c = (float*)(ws + o_bl1);
  float* w2cat = (float*)(ws + o_w2c);
  int* mbc = (int*)(ws + o_mbc);
  int* pbc = (int*)(ws + o_pbc);
  int* mbh = (int*)(ws + o_mbh);
  int* pbh = (int*)(ws + o_pbh);
  int* mbed = (int*)(ws + o_mbed);
  int* pbed = (int*)(ws + o_pbed);
  float* mh1T = (float*)(ws + o_mh1T);
  float* mh2T = (float*)(ws + o_mh2T);
  float* ph1T = (float*)(ws + o_ph1T);
  float* ph2T = (float*)(ws + o_ph2T);
  float* fc1T = (float*)(ws + o_fc1T);
  float* fc2T = (float*)(ws + o_fc2T);
  float* xc = (float*)(ws + o_xc);
  float* t1 = (float*)(ws + o_t1);
  float* t2 = (float*)(ws + o_t2);
  float* th = (float*)(ws + o_th);
  float* invM = (float*)(ws + o_invM);
  float* invP = (float*)(ws + o_invP);
  int2* mbinned = (int2*)hA;
  int2* pbinned = (int2*)aggh;  // consumed by k_build before aggh is written

  // weight prep (tiny, tiled transposes — coalesced both sides)
  k_prepw<<<(108 * 108 + 255) / 256, 256, 0, stream>>>(c1_Wl, c1_Wr, c1_bl, c2_Wl, c2_Wr,
                                                       w1cat, bl1c, w2cat);
  {
    auto tg = [](int R, int C) { return dim3((C + 31) / 32, (R + 31) / 32); };
    k_transT<<<tg(256, DM), 256, 0, stream>>>(mol_W1, mh1T, 256, DM);
    k_transT<<<tg(112, 256), 256, 0, stream>>>(mol_W2, mh2T, 112, 256);
    k_transT<<<tg(256, DP2), 256, 0, stream>>>(pro_W1, ph1T, 256, DP2);
    k_transT<<<tg(144, 256), 256, 0, stream>>>(pro_W2, ph2T, 144, 256);
    k_transT<<<tg(1024, 256), 256, 0, stream>>>(fc1_W, fc1T, 1024, 256);
    k_transT<<<tg(512, 1024), 256, 0, stream>>>(fc2_W, fc2T, 512, 1024);
  }

  // ===== MOL branch (f32 — APPNP amplifies magnitudes; keep exact) =====
  constexpr int SHM = 8;
  constexpr int NBM = (NM + (1 << SHM) - 1) >> SHM;
  hipMemsetAsync(mbh, 0, 512 * 4, stream);
  k_bhist<SHM><<<(EM + 4095) / 4096, 256, 0, stream>>>(m_row, mbh, EM);
  k_scanb<<<1, 512, 0, stream>>>(mbh, mbed, mbc, NBM, EM);
  k_bin<SHM><<<(EM + 4095) / 4096, 256, 0, stream>>>(m_col, m_row, mbc, mbinned, EM);
  k_build<SHM><<<NBM, 256, 0, stream>>>(mbinned, mbed, mdeg, mstart, mcsr, NM);
  k_bstart<<<(NM + 255) / 256, 256, 0, stream>>>(m_batch, mbs, NM);
  k_inv<<<1, 128, 0, stream>>>(mbs, invM);

  int gb_m = (NM * 64 + 255) / 256;
  k_pool_seg<DM, 3, false><<<B, 256, 0, stream>>>(mol_x, mbs, poolM, 0.05f);
  k_gatherv<DM, false><<<gb_m, 256, 0, stream>>>(mol_x, mstart, mdeg, mcsr, hA, NM, DM);
  k_pool_seg<DM, 3, true><<<B, 256, 0, stream>>>(hA, mbs, poolM, 0.2375f);
  k_gatherv<DM, false><<<gb_m, 256, 0, stream>>>(hA, mstart, mdeg, mcsr, hB, NM, DM);
  k_pool_seg<DM, 3, true><<<B, 256, 0, stream>>>(hB, mbs, poolM, 0.2375f);
  k_gatherv<DM, false><<<gb_m, 256, 0, stream>>>(hB, mstart, mdeg, mcsr, hA, NM, DM);
  k_pool_seg<DM, 3, true><<<B, 256, 0, stream>>>(hA, mbs, poolM, 0.2375f);
  k_gatherv<DM, false><<<gb_m, 256, 0, stream>>>(hA, mstart, mdeg, mcsr, hB, NM, DM);
  k_pool_seg<DM, 3, true><<<B, 256, 0, stream>>>(hB, mbs, poolM, 0.2375f);
  {
    dim3 g1(1, B / 8);
    k_mlp<DM, 256, true><<<g1, 256, 0, stream>>>(poolM, DM, invM, mh1T, mol_b1, th, 256, 0);
    k_mlp<256, 112, false><<<g1, 256, 0, stream>>>(th, 256, nullptr, mh2T, mol_b2, xc, 256, 0);
  }

  // ===== PRO branch (bf16 feature rows; mean-aggr keeps noise bounded) =====
  constexpr int SHP = 9;
  constexpr int NBP = (NP + (1 << SHP) - 1) >> SHP;
  hipMemsetAsync(pbh, 0, 512 * 4, stream);
  hipMemsetAsync(poolP, 0, (size_t)B * DP2 * 4, stream);
  k_bhist<SHP><<<(EP + 4095) / 4096, 256, 0, stream>>>(p_e1, pbh, EP);
  k_scanb<<<1, 512, 0, stream>>>(pbh, pbed, pbc, NBP, EP);
  k_bin<SHP><<<(EP + 4095) / 4096, 256, 0, stream>>>(p_e0, p_e1, pbc, pbinned, EP);
  k_build<SHP><<<NBP, 256, 0, stream>>>(pbinned, pbed, pdeg, pstart, pcsr, NP);
  k_bstart<<<(NP + 255) / 256, 256, 0, stream>>>(p_batch, pbs, NP);
  k_inv<<<1, 128, 0, stream>>>(pbs, invP);
  k_cast<<<(NP * 27 + 255) / 256, 256, 0, stream>>>(pro_x, pxh, NP);

  int gb_p = (NP * 64 + 255) / 256;
  k_gatherh<<<gb_p, 256, 0, stream>>>(pxh, pstart, pdeg, pcsr, aggh, NP);
  k_sage1c<<<(NP + 63) / 64, 256, 0, stream>>>(pro_x, aggh, w1cat, bl1c, xt1h, NP);
  k_gatherh<<<gb_p, 256, 0, stream>>>(xt1h, pstart, pdeg, pcsr, aggh, NP);
  k_sage2c<8><<<B * 8, 256, 0, stream>>>(xt1h, aggh, w2cat, c2_bl, pbs, poolP);
  {
    dim3 g1(1, B / 8);
    k_mlp<DP2, 256, true><<<g1, 256, 0, stream>>>(poolP, DP2, invP, ph1T, pro_b1, th, 256, 0);
    k_mlp<256, 144, false><<<g1, 256, 0, stream>>>(th, 256, nullptr, ph2T, pro_b2, xc, 256, 112);
  }

  // ===== final MLP: xc -> 1024 relu -> 512 relu -> 1 =====
  {
    dim3 gA(4, B / 8);
    k_mlp<256, 1024, true><<<gA, 256, 0, stream>>>(xc, 256, nullptr, fc1T, fc1_b, t1, 1024, 0);
    dim3 gB(2, B / 8);
    k_mlp<1024, 512, true><<<gB, 256, 0, stream>>>(t1, 1024, nullptr, fc2T, fc2_b, t2, 512, 0);
    k_gemv1<<<B, 64, 0, stream>>>(t2, out_W, out_b, out);
  }
}

// Round 12
// 903.566 us; speedup vs baseline: 1.5343x; 1.3991x over previous
//
#include <hip/hip_runtime.h>

#define K256 __launch_bounds__(256)

constexpr int B = 128;
constexpr int NM = 100000, EM = 400000;
constexpr int NP = 200000, EP = 3200000;
constexpr int DM = 78, DPK = 54, DP2 = 108;
constexpr int XH = 32;  // bf16 row stride in ushort2 units (64 bf16 = 128 B, line-aligned)

// ---- bf16 helpers (RTNE) ----
__device__ __forceinline__ float b2f(unsigned short u) {
  return __uint_as_float((unsigned int)u << 16);
}
__device__ __forceinline__ unsigned short f2b(float f) {
  unsigned int b = __float_as_uint(f);
  return (unsigned short)((b + 0x7fffu + ((b >> 16) & 1u)) >> 16);
}

// ---------- CSR build: bucket histogram (LDS-aggregated, no per-node atomics) ----------
template <int SH>
__global__ void K256 k_bhist(const int* __restrict__ dst, int* __restrict__ bhist, int E) {
  __shared__ int lh[512];
  int tid = threadIdx.x;
  for (int t = tid; t < 512; t += 256) lh[t] = 0;
  __syncthreads();
  int c0 = blockIdx.x * 4096;
#pragma unroll
  for (int k = 0; k < 16; k++) {
    int e = c0 + k * 256 + tid;
    if (e < E) atomicAdd(&lh[dst[e] >> SH], 1);
  }
  __syncthreads();
  for (int t = tid; t < 512; t += 256) {
    int c = lh[t];
    if (c) atomicAdd(&bhist[t], c);
  }
}

// one-block scan of bucket counts -> bed (exclusive, +total) and bcur
__global__ void k_scanb(const int* __restrict__ bhist, int* __restrict__ bed,
                        int* __restrict__ bcur, int NB, int E) {
  __shared__ int s[512];
  int tid = threadIdx.x;
  int v = (tid < NB) ? bhist[tid] : 0;
  s[tid] = v;
  __syncthreads();
  for (int off = 1; off < 512; off <<= 1) {
    int t = (tid >= off) ? s[tid - off] : 0;
    __syncthreads();
    s[tid] += t;
    __syncthreads();
  }
  int excl = s[tid] - v;
  if (tid < NB) {
    bed[tid] = excl;
    bcur[tid] = excl;
  }
  if (tid == NB - 1) bed[NB] = E;
}

// Pass A: bucket-grouped edge binning (counting-sort per 4096-edge chunk).
template <int SH>
__global__ void K256 k_bin(const int* __restrict__ src, const int* __restrict__ dst,
                           int* __restrict__ bcur, int2* __restrict__ binned, int E) {
  __shared__ int lh[512];
  __shared__ int gbase[512];
  int c0 = blockIdx.x * 4096;
  int tid = threadIdx.x;
  for (int t = tid; t < 512; t += 256) lh[t] = 0;
  __syncthreads();
  int r[16], dcache[16];
#pragma unroll
  for (int k = 0; k < 16; k++) {
    int e = c0 + k * 256 + tid;
    if (e < E) {
      int d = dst[e];
      dcache[k] = d;
      r[k] = atomicAdd(&lh[d >> SH], 1);
    }
  }
  __syncthreads();
  for (int b = tid; b < 512; b += 256) {
    int c = lh[b];
    gbase[b] = c ? atomicAdd(&bcur[b], c) : 0;
  }
  __syncthreads();
#pragma unroll
  for (int k = 0; k < 16; k++) {
    int e = c0 + k * 256 + tid;
    if (e < E) {
      int d = dcache[k];
      binned[gbase[d >> SH] + r[k]] = make_int2(src[e], d);
    }
  }
}

// Pass B (fused): per-bucket count -> LDS scan -> deg/starts write -> CSR fill.
template <int SH>
__global__ void K256 k_build(const int2* __restrict__ binned, const int* __restrict__ bed,
                             int* __restrict__ deg, int* __restrict__ starts,
                             int* __restrict__ csr, int N) {
  constexpr int NN = 1 << SH;
  constexpr int P = NN / 256;
  __shared__ int lcnt[NN];
  __shared__ int lpair[256];
  int b = blockIdx.x, base = b << SH, tid = threadIdx.x;
  int nn = min(N - base, NN);
  for (int t = tid; t < NN; t += 256) lcnt[t] = 0;
  __syncthreads();
  int e0 = bed[b], e1 = bed[b + 1];
  for (int e = e0 + tid; e < e1; e += 256) atomicAdd(&lcnt[binned[e].y - base], 1);
  __syncthreads();
  int loc[P];
  int psum = 0;
#pragma unroll
  for (int p = 0; p < P; p++) {
    loc[p] = lcnt[tid * P + p];
    psum += loc[p];
  }
  lpair[tid] = psum;
  __syncthreads();
  for (int off = 1; off < 256; off <<= 1) {
    int t = (tid >= off) ? lpair[tid - off] : 0;
    __syncthreads();
    lpair[tid] += t;
    __syncthreads();
  }
  int run = lpair[tid] - psum;
  __syncthreads();  // done reading lcnt as counts; reuse as cursors
#pragma unroll
  for (int p = 0; p < P; p++) {
    int i = tid * P + p;
    int st = e0 + run;
    if (i < nn) {
      deg[base + i] = loc[p];
      starts[base + i] = st;
    }
    lcnt[i] = st;
    run += loc[p];
  }
  __syncthreads();
  for (int e = e0 + tid; e < e1; e += 256) {
    int2 sd = binned[e];
    int p = atomicAdd(&lcnt[sd.y - base], 1);
    csr[p] = sd.x;
  }
}

// ---------- batch segment starts (batch is sorted) ----------
__global__ void K256 k_bstart(const int* __restrict__ batch, int* __restrict__ bstart, int N) {
  int i = blockIdx.x * 256 + threadIdx.x;
  if (i < N) {
    int b = batch[i];
    int pb = (i == 0) ? -1 : batch[i - 1];
    for (int bb = pb + 1; bb <= b; bb++) bstart[bb] = i;
    if (i == N - 1)
      for (int bb = b + 1; bb <= B; bb++) bstart[bb] = N;
  }
}

__global__ void k_inv(const int* __restrict__ bstart, float* __restrict__ inv) {
  int b = threadIdx.x;
  if (b < B) inv[b] = 1.f / fmaxf((float)(bstart[b + 1] - bstart[b]), 1.f);
}

// ---------- tiled transpose: out[c*R + r] = in[r*C + c], coalesced both sides ----------
__global__ void K256 k_transT(const float* __restrict__ in, float* __restrict__ out, int R,
                              int C) {
  __shared__ float t[32][33];
  int cb = blockIdx.x * 32, rb = blockIdx.y * 32;
  int tx = threadIdx.x & 31, ty = threadIdx.x >> 5;
  for (int i = ty; i < 32; i += 8) {
    int r = rb + i, c = cb + tx;
    if (r < R && c < C) t[i][tx] = in[(size_t)r * C + c];
  }
  __syncthreads();
  for (int i = ty; i < 32; i += 8) {
    int c = cb + i, r = rb + tx;
    if (r < R && c < C) out[(size_t)c * R + r] = t[tx][i];
  }
}

// ---------- weight prep: cat-form transposed weights ----------
__global__ void K256 k_prepw(const float* __restrict__ c1Wl, const float* __restrict__ c1Wr,
                             const float* __restrict__ c1bl, const float* __restrict__ c2Wl,
                             const float* __restrict__ c2Wr, float* __restrict__ w1cat,
                             float* __restrict__ bl1c, float* __restrict__ w2cat) {
  int i = blockIdx.x * 256 + threadIdx.x;
  if (i < 108 * 56) {
    int k = i / 56, o = i - k * 56;
    w1cat[i] = (o < 54) ? ((k < 54) ? c1Wl[o * 54 + k] : c1Wr[o * 54 + (k - 54)]) : 0.f;
  }
  if (i < 108 * 108) {
    int k = i / 108, o = i - k * 108;
    w2cat[i] = (k < 54) ? c2Wl[o * 54 + k] : c2Wr[o * 54 + (k - 54)];
  }
  if (i < 56) bl1c[i] = (i < 54) ? c1bl[i] : 0.f;
}

// ---------- cast pro_x (f32 stride 54) -> bf16 rows (stride XH ushort2) ----------
__global__ void K256 k_cast(const float* __restrict__ x, ushort2* __restrict__ xh, int N) {
  int t = blockIdx.x * 256 + threadIdx.x;
  if (t < N * 27) {
    int n = t / 27, j = t - n * 27;
    float2 v = *(const float2*)(x + (size_t)n * 54 + 2 * j);
    xh[(size_t)n * XH + j] = make_ushort2(f2b(v.x), f2b(v.y));
  }
}

// ---------- bf16 gather: wave per node, 27 active lanes/half, 8-deep edge ILP ----------
__global__ void K256 k_gatherh(const ushort2* __restrict__ xh, const int* __restrict__ starts,
                               const int* __restrict__ deg, const int* __restrict__ csr,
                               ushort2* __restrict__ outh, int N) {
  int wid = (blockIdx.x * 256 + threadIdx.x) >> 6;
  int lane = threadIdx.x & 63;
  if (wid >= N) return;
  int s = starts[wid], d = deg[wid];
  const int* cp = csr + s;
  int half = lane >> 5, sl = lane & 31;
  bool act = sl < 27;
  float ax = 0.f, ay = 0.f, bx = 0.f, by = 0.f;
  float cx = 0.f, cy = 0.f, dx = 0.f, dy = 0.f;
  int j = 0;
  for (; j + 8 <= d; j += 8) {
    if (act) {
      ushort2 v0 = xh[(size_t)cp[j + half] * XH + sl];
      ushort2 v1 = xh[(size_t)cp[j + 2 + half] * XH + sl];
      ushort2 v2 = xh[(size_t)cp[j + 4 + half] * XH + sl];
      ushort2 v3 = xh[(size_t)cp[j + 6 + half] * XH + sl];
      ax += b2f(v0.x);
      ay += b2f(v0.y);
      bx += b2f(v1.x);
      by += b2f(v1.y);
      cx += b2f(v2.x);
      cy += b2f(v2.y);
      dx += b2f(v3.x);
      dy += b2f(v3.y);
    }
  }
  for (; j + 2 <= d; j += 2) {
    if (act) {
      ushort2 v = xh[(size_t)cp[j + half] * XH + sl];
      ax += b2f(v.x);
      ay += b2f(v.y);
    }
  }
  if (j < d && half == 0 && act) {  // odd tail: single edge
    ushort2 v = xh[(size_t)cp[j] * XH + sl];
    ax += b2f(v.x);
    ay += b2f(v.y);
  }
  ax += bx + cx + dx;
  ay += by + cy + dy;
  ax += __shfl_xor(ax, 32, 64);
  ay += __shfl_xor(ay, 32, 64);
  if (half == 0 && act) {
    float inv = 1.f / fmaxf((float)d, 1.f);
    outh[(size_t)wid * XH + sl] = make_ushort2(f2b(ax * inv), f2b(ay * inv));
  }
}

// ---------- f32 gather (mol): wave per node, float2 lanes, 4-deep edge ILP ----------
template <int D, bool MEAN>
__global__ void K256 k_gatherv(const float* __restrict__ x, const int* __restrict__ starts,
                               const int* __restrict__ deg, const int* __restrict__ csr,
                               float* __restrict__ out, int N, int ostride) {
  constexpr int NF2 = D / 2;
  int wid = (blockIdx.x * 256 + threadIdx.x) >> 6;
  int lane = threadIdx.x & 63;
  if (wid >= N) return;
  int s = starts[wid], d = deg[wid];
  const int* cp = csr + s;
  bool act = lane < NF2;
  float ax = 0.f, ay = 0.f, bx = 0.f, by = 0.f;
  int j = 0;
  for (; j + 4 <= d; j += 4) {
    if (act) {
      float2 v0 = ((const float2*)(x + (size_t)cp[j] * D))[lane];
      float2 v1 = ((const float2*)(x + (size_t)cp[j + 1] * D))[lane];
      float2 v2 = ((const float2*)(x + (size_t)cp[j + 2] * D))[lane];
      float2 v3 = ((const float2*)(x + (size_t)cp[j + 3] * D))[lane];
      ax += v0.x + v2.x;
      ay += v0.y + v2.y;
      bx += v1.x + v3.x;
      by += v1.y + v3.y;
    }
  }
  for (; j < d; j++) {
    if (act) {
      float2 v = ((const float2*)(x + (size_t)cp[j] * D))[lane];
      ax += v.x;
      ay += v.y;
    }
  }
  ax += bx;
  ay += by;
  if (act) {
    float inv = MEAN ? 1.f / fmaxf((float)d, 1.f) : 1.f;
    float2* op = (float2*)(out + (size_t)wid * ostride);
    float2 w;
    w.x = ax * inv;
    w.y = ay * inv;
    op[lane] = w;
  }
}

// ---------- segmented pooling, split + ILP-4; flushes with atomics (pooled pre-zeroed) ----------
template <int D, int SPLIT>
__global__ void K256 k_pool_seg2(const float* __restrict__ x, const int* __restrict__ bstart,
                                 float* __restrict__ pooled, float coef) {
  constexpr int NPB = 256 / D;
  __shared__ float sp[D * NPB];
  int b = blockIdx.x / SPLIT;
  int sidx = blockIdx.x - b * SPLIT;
  int tid = threadIdx.x;
  int r0 = bstart[b], r1 = bstart[b + 1];
  int len = r1 - r0;
  int per = (len + SPLIT - 1) / SPLIT;
  int s0 = r0 + sidx * per;
  int s1 = min(r1, s0 + per);
  if (tid < D * NPB) {
    int ioff = tid / D, f = tid - ioff * D;
    float a0 = 0.f, a1 = 0.f, a2 = 0.f, a3 = 0.f;
    int i = s0 + ioff;
    for (; i + 3 * NPB < s1; i += 4 * NPB) {
      a0 += x[(size_t)i * D + f];
      a1 += x[(size_t)(i + NPB) * D + f];
      a2 += x[(size_t)(i + 2 * NPB) * D + f];
      a3 += x[(size_t)(i + 3 * NPB) * D + f];
    }
    for (; i < s1; i += NPB) a0 += x[(size_t)i * D + f];
    sp[tid] = (a0 + a1) + (a2 + a3);
  }
  __syncthreads();
  if (tid < D) {
    float s = 0.f;
#pragma unroll
    for (int g = 0; g < NPB; g++) s += sp[g * D + tid];
    s *= coef;
    if (s != 0.f) atomicAdd(&pooled[b * D + tid], s);
  }
}

// ---------- SAGE conv1 cat-form: 64-node tile, 4 waves x 14 outputs; bf16 agg in, bf16 out ----------
__global__ void __launch_bounds__(256, 4) k_sage1c(
    const float* __restrict__ x, const ushort2* __restrict__ aggh,
    const float* __restrict__ wcat, const float* __restrict__ blc,
    ushort2* __restrict__ outh, int N) {
  __shared__ float scat[64 * 109];
  int base = blockIdx.x * 64;
  int nn = min(N - base, 64);
  int tid = threadIdx.x;
  for (int t = tid; t < nn * 27; t += 256) {
    int n = t / 27, j = t - n * 27;
    ushort2 va = aggh[(size_t)(base + n) * XH + j];
    float2 vx = *(const float2*)(x + (size_t)(base + n) * 54 + 2 * j);
    float* sr = scat + n * 109;
    sr[2 * j] = b2f(va.x);
    sr[2 * j + 1] = b2f(va.y);
    sr[54 + 2 * j] = vx.x;
    sr[54 + 2 * j + 1] = vx.y;
  }
  __syncthreads();
  int w = tid >> 6, lane = tid & 63;
  int obase = __builtin_amdgcn_readfirstlane(w * 14);
  if (lane >= nn) return;
  float acc[14];
#pragma unroll
  for (int o = 0; o < 14; o++) acc[o] = blc[obase + o];
  const float* rs = scat + lane * 109;
#pragma unroll 2
  for (int k = 0; k < 108; k++) {
    float v = rs[k];
    const float* wr = wcat + k * 56 + obase;
#pragma unroll
    for (int o = 0; o < 14; o++) acc[o] += v * wr[o];
  }
  ushort2* op = outh + (size_t)(base + lane) * XH + (obase >> 1);
#pragma unroll
  for (int o = 0; o < 7; o++)
    op[o] = make_ushort2(f2b(fmaxf(acc[2 * o], 0.f)), f2b(fmaxf(acc[2 * o + 1], 0.f)));
}

// ---------- conv2 + pool cat-form: 64-node tile, 4 waves x 27 outputs; bf16 inputs ----------
template <int SPLIT>
__global__ void __launch_bounds__(256, 4) k_sage2c(
    const ushort2* __restrict__ xt1h, const ushort2* __restrict__ aggh,
    const float* __restrict__ wcat, const float* __restrict__ bl,
    const int* __restrict__ bstart, float* __restrict__ pooled) {
  __shared__ float scat[64 * 109];
  int b = blockIdx.x / SPLIT;
  int sidx = blockIdx.x - b * SPLIT;
  int tid = threadIdx.x;
  int w = tid >> 6, lane = tid & 63;
  int obase = __builtin_amdgcn_readfirstlane(w * 27);
  int r0 = bstart[b], r1 = bstart[b + 1];
  int len = r1 - r0;
  int per = (len + SPLIT - 1) / SPLIT;
  int s0 = r0 + sidx * per;
  int s1 = min(r1, s0 + per);
  float pool[27];
#pragma unroll
  for (int o = 0; o < 27; o++) pool[o] = 0.f;
  for (int tb = s0; tb < s1; tb += 64) {
    int nn = min(s1 - tb, 64);
    __syncthreads();
    for (int t = tid; t < nn * 27; t += 256) {
      int n = t / 27, j = t - n * 27;
      ushort2 va = aggh[(size_t)(tb + n) * XH + j];
      ushort2 vx = xt1h[(size_t)(tb + n) * XH + j];
      float* sr = scat + n * 109;
      sr[2 * j] = b2f(va.x);
      sr[2 * j + 1] = b2f(va.y);
      sr[54 + 2 * j] = b2f(vx.x);
      sr[54 + 2 * j + 1] = b2f(vx.y);
    }
    __syncthreads();
    if (lane < nn) {
      float acc[27];
#pragma unroll
      for (int o = 0; o < 27; o++) acc[o] = bl[obase + o];
      const float* rs = scat + lane * 109;
#pragma unroll 2
      for (int k = 0; k < 108; k++) {
        float v = rs[k];
        const float* wr = wcat + k * 108 + obase;
#pragma unroll
        for (int o = 0; o < 27; o++) acc[o] += v * wr[o];
      }
#pragma unroll
      for (int o = 0; o < 27; o++) pool[o] += fmaxf(acc[o], 0.f);
    }
  }
#pragma unroll
  for (int o = 0; o < 27; o++) {
#pragma unroll
    for (int off = 1; off < 64; off <<= 1) pool[o] += __shfl_xor(pool[o], off, 64);
  }
  if (lane == 0) {
    float* pb = pooled + b * DP2 + obase;
#pragma unroll
    for (int o = 0; o < 27; o++)
      if (pool[o] != 0.f) atomicAdd(&pb[o], pool[o]);
  }
}

// ---------- tiny GEMM: Y[128][DOUT](+ycol0) = act(X[128][DIN] (*rs) @ WT + b) ----------
template <int DIN, int DOUT, bool RELU>
__global__ void K256 k_mlp(const float* __restrict__ X, int xstride,
                           const float* __restrict__ rs, const float* __restrict__ WT,
                           const float* __restrict__ bias, float* __restrict__ Y,
                           int ystride, int ycol0) {
  constexpr int BT = 8;
  __shared__ float Xs[BT][DIN];
  int tid = threadIdx.x;
  int ob = blockIdx.x * 256 + tid;
  int bb = blockIdx.y * BT;
  for (int t = tid; t < BT * DIN; t += 256) {
    int i = t / DIN, k = t - i * DIN;
    float v = X[(size_t)(bb + i) * xstride + k];
    if (rs) v *= rs[bb + i];
    Xs[i][k] = v;
  }
  __syncthreads();
  int o = (ob < DOUT) ? ob : (DOUT - 1);
  float bv = bias[o];
  float acc[BT];
#pragma unroll
  for (int i = 0; i < BT; i++) acc[i] = bv;
#pragma unroll 4
  for (int k = 0; k < DIN; k++) {
    float w = WT[(size_t)k * DOUT + o];
#pragma unroll
    for (int i = 0; i < BT; i++) acc[i] += Xs[i][k] * w;
  }
  if (ob < DOUT) {
#pragma unroll
    for (int i = 0; i < BT; i++) {
      float v = RELU ? fmaxf(acc[i], 0.f) : acc[i];
      Y[(size_t)(bb + i) * ystride + ycol0 + ob] = v;
    }
  }
}

// ---------- final 512 -> 1 GEMV: one wave per batch ----------
__global__ void __launch_bounds__(64) k_gemv1(const float* __restrict__ t2,
                                              const float* __restrict__ W3,
                                              const float* __restrict__ b3,
                                              float* __restrict__ out) {
  int b = blockIdx.x, lane = threadIdx.x;
  float a = 0.f;
  const float* row = t2 + (size_t)b * 512;
#pragma unroll 2
  for (int k = lane; k < 512; k += 64) a += row[k] * W3[k];
#pragma unroll
  for (int off = 32; off > 0; off >>= 1) a += __shfl_down(a, off, 64);
  if (lane == 0) out[b] = a + b3[0];
}

__global__ void k_report(float* out, float v, int n) {
  int i = blockIdx.x * 256 + threadIdx.x;
  if (i < n) out[i] = v;
}

extern "C" void kernel_launch(void* const* d_in, const int* in_sizes, int n_in,
                              void* d_out, int out_size, void* d_ws, size_t ws_size,
                              hipStream_t stream) {
  (void)in_sizes; (void)n_in;
  const float* mol_x = (const float*)d_in[0];
  const int* m_ei = (const int*)d_in[1];
  const int* m_batch = (const int*)d_in[2];
  const float* pro_x = (const float*)d_in[3];
  const int* p_ei = (const int*)d_in[4];
  const int* p_batch = (const int*)d_in[5];
  const float* mol_W1 = (const float*)d_in[6];
  const float* mol_b1 = (const float*)d_in[7];
  const float* mol_W2 = (const float*)d_in[8];
  const float* mol_b2 = (const float*)d_in[9];
  const float* c1_Wl = (const float*)d_in[10];
  const float* c1_bl = (const float*)d_in[11];
  const float* c1_Wr = (const float*)d_in[12];
  const float* c2_Wl = (const float*)d_in[13];
  const float* c2_bl = (const float*)d_in[14];
  const float* c2_Wr = (const float*)d_in[15];
  const float* pro_W1 = (const float*)d_in[16];
  const float* pro_b1 = (const float*)d_in[17];
  const float* pro_W2 = (const float*)d_in[18];
  const float* pro_b2 = (const float*)d_in[19];
  const float* fc1_W = (const float*)d_in[20];
  const float* fc1_b = (const float*)d_in[21];
  const float* fc2_W = (const float*)d_in[22];
  const float* fc2_b = (const float*)d_in[23];
  const float* out_W = (const float*)d_in[24];
  const float* out_b = (const float*)d_in[25];
  float* out = (float*)d_out;
  char* ws = (char*)d_ws;

  const int* m_row = m_ei;       // dst
  const int* m_col = m_ei + EM;  // src
  const int* p_e0 = p_ei;        // src
  const int* p_e1 = p_ei + EP;   // dst

  auto al = [](size_t x) { return (x + 255) & ~(size_t)255; };

  size_t o = 0;
  size_t o_pdeg = o;   o += al((size_t)NP * 4);
  size_t o_pstart = o; o += al((size_t)NP * 4);
  size_t o_pcsr = o;   o += al((size_t)EP * 4);
  size_t o_aggh = o;   o += al((size_t)NP * XH * 4);  // bf16 rows; also pro binned
  size_t o_xt1h = o;   o += al((size_t)NP * XH * 4);
  size_t o_pxh = o;    o += al((size_t)NP * XH * 4);
  size_t pro_end = o;

  o = 0;
  size_t o_mdeg = o;   o += al((size_t)NM * 4);
  size_t o_mstart = o; o += al((size_t)NM * 4);
  size_t o_mcsr = o;   o += al((size_t)EM * 4);
  size_t o_hA = o;     o += al((size_t)NM * DM * 4);  // also mol binned
  size_t o_hB = o;     o += al((size_t)NM * DM * 4);
  size_t mol_end = o;

  size_t tail = al(pro_end > mol_end ? pro_end : mol_end);
  size_t o_poolM = tail; tail += al((size_t)B * DM * 4);
  size_t o_poolP = tail; tail += al((size_t)B * DP2 * 4);
  size_t o_mbs = tail;   tail += al((size_t)(B + 1) * 4);
  size_t o_pbs = tail;   tail += al((size_t)(B + 1) * 4);
  size_t o_w1c = tail;   tail += al((size_t)108 * 56 * 4);
  size_t o_bl1 = tail;   tail += al(56 * 4);
  size_t o_w2c = tail;   tail += al((size_t)108 * 108 * 4);
  size_t o_mbc = tail;   tail += al(512 * 4);
  size_t o_pbc = tail;   tail += al(512 * 4);
  size_t o_mbh = tail;   tail += al(512 * 4);
  size_t o_pbh = tail;   tail += al(512 * 4);
  size_t o_mbed = tail;  tail += al(513 * 4);
  size_t o_pbed = tail;  tail += al(513 * 4);
  // MLP machinery
  size_t o_mh1T = tail;  tail += al((size_t)DM * 256 * 4);
  size_t o_mh2T = tail;  tail += al((size_t)256 * 112 * 4);
  size_t o_ph1T = tail;  tail += al((size_t)DP2 * 256 * 4);
  size_t o_ph2T = tail;  tail += al((size_t)256 * 144 * 4);
  size_t o_fc1T = tail;  tail += al((size_t)256 * 1024 * 4);
  size_t o_fc2T = tail;  tail += al((size_t)1024 * 512 * 4);
  size_t o_xc = tail;    tail += al((size_t)B * 256 * 4);
  size_t o_t1 = tail;    tail += al((size_t)B * 1024 * 4);
  size_t o_t2 = tail;    tail += al((size_t)B * 512 * 4);
  size_t o_th = tail;    tail += al((size_t)B * 256 * 4);
  size_t o_invM = tail;  tail += al(B * 4);
  size_t o_invP = tail;  tail += al(B * 4);

  if (ws_size < tail) {
    k_report<<<1, 256, 0, stream>>>(out, (float)(ws_size >> 20), out_size);
    return;
  }

  int* mdeg = (int*)(ws + o_mdeg);
  int* mstart = (int*)(ws + o_mstart);
  int* mcsr = (int*)(ws + o_mcsr);
  float* hA = (float*)(ws + o_hA);
  float* hB = (float*)(ws + o_hB);
  int* pdeg = (int*)(ws + o_pdeg);
  int* pstart = (int*)(ws + o_pstart);
  int* pcsr = (int*)(ws + o_pcsr);
  ushort2* aggh = (ushort2*)(ws + o_aggh);
  ushort2* xt1h = (ushort2*)(ws + o_xt1h);
  ushort2* pxh = (ushort2*)(ws + o_pxh);
  float* poolM = (float*)(ws + o_poolM);
  float* poolP = (float*)(ws + o_poolP);
  int* mbs = (int*)(ws + o_mbs);
  int* pbs = (int*)(ws + o_pbs);
  float* w1cat = (float*)(ws + o_w1c);
  float* bl1c = (float*)(ws + o_bl1);
  float* w2cat = (float*)(ws + o_w2c);
  int* mbc = (int*)(ws + o_mbc);
  int* pbc = (int*)(ws + o_pbc);
  int* mbh = (int*)(ws + o_mbh);
  int* pbh = (int*)(ws + o_pbh);
  int* mbed = (int*)(ws + o_mbed);
  int* pbed = (int*)(ws + o_pbed);
  float* mh1T = (float*)(ws + o_mh1T);
  float* mh2T = (float*)(ws + o_mh2T);
  float* ph1T = (float*)(ws + o_ph1T);
  float* ph2T = (float*)(ws + o_ph2T);
  float* fc1T = (float*)(ws + o_fc1T);
  float* fc2T = (float*)(ws + o_fc2T);
  float* xc = (float*)(ws + o_xc);
  float* t1 = (float*)(ws + o_t1);
  float* t2 = (float*)(ws + o_t2);
  float* th = (float*)(ws + o_th);
  float* invM = (float*)(ws + o_invM);
  float* invP = (float*)(ws + o_invP);
  int2* mbinned = (int2*)hA;
  int2* pbinned = (int2*)aggh;  // consumed by k_build before aggh is written

  // weight prep (tiny, tiled transposes — coalesced both sides)
  k_prepw<<<(108 * 108 + 255) / 256, 256, 0, stream>>>(c1_Wl, c1_Wr, c1_bl, c2_Wl, c2_Wr,
                                                       w1cat, bl1c, w2cat);
  {
    auto tg = [](int R, int C) { return dim3((C + 31) / 32, (R + 31) / 32); };
    k_transT<<<tg(256, DM), 256, 0, stream>>>(mol_W1, mh1T, 256, DM);
    k_transT<<<tg(112, 256), 256, 0, stream>>>(mol_W2, mh2T, 112, 256);
    k_transT<<<tg(256, DP2), 256, 0, stream>>>(pro_W1, ph1T, 256, DP2);
    k_transT<<<tg(144, 256), 256, 0, stream>>>(pro_W2, ph2T, 144, 256);
    k_transT<<<tg(1024, 256), 256, 0, stream>>>(fc1_W, fc1T, 1024, 256);
    k_transT<<<tg(512, 1024), 256, 0, stream>>>(fc2_W, fc2T, 512, 1024);
  }

  // ===== MOL branch (f32 — APPNP amplifies magnitudes; keep exact) =====
  constexpr int SHM = 8;
  constexpr int NBM = (NM + (1 << SHM) - 1) >> SHM;
  hipMemsetAsync(mbh, 0, 512 * 4, stream);
  hipMemsetAsync(poolM, 0, (size_t)B * DM * 4, stream);
  k_bhist<SHM><<<(EM + 4095) / 4096, 256, 0, stream>>>(m_row, mbh, EM);
  k_scanb<<<1, 512, 0, stream>>>(mbh, mbed, mbc, NBM, EM);
  k_bin<SHM><<<(EM + 4095) / 4096, 256, 0, stream>>>(m_col, m_row, mbc, mbinned, EM);
  k_build<SHM><<<NBM, 256, 0, stream>>>(mbinned, mbed, mdeg, mstart, mcsr, NM);
  k_bstart<<<(NM + 255) / 256, 256, 0, stream>>>(m_batch, mbs, NM);
  k_inv<<<1, 128, 0, stream>>>(mbs, invM);

  int gb_m = (NM * 64 + 255) / 256;
  k_pool_seg2<DM, 8><<<B * 8, 256, 0, stream>>>(mol_x, mbs, poolM, 0.05f);
  k_gatherv<DM, false><<<gb_m, 256, 0, stream>>>(mol_x, mstart, mdeg, mcsr, hA, NM, DM);
  k_pool_seg2<DM, 8><<<B * 8, 256, 0, stream>>>(hA, mbs, poolM, 0.2375f);
  k_gatherv<DM, false><<<gb_m, 256, 0, stream>>>(hA, mstart, mdeg, mcsr, hB, NM, DM);
  k_pool_seg2<DM, 8><<<B * 8, 256, 0, stream>>>(hB, mbs, poolM, 0.2375f);
  k_gatherv<DM, false><<<gb_m, 256, 0, stream>>>(hB, mstart, mdeg, mcsr, hA, NM, DM);
  k_pool_seg2<DM, 8><<<B * 8, 256, 0, stream>>>(hA, mbs, poolM, 0.2375f);
  k_gatherv<DM, false><<<gb_m, 256, 0, stream>>>(hA, mstart, mdeg, mcsr, hB, NM, DM);
  k_pool_seg2<DM, 8><<<B * 8, 256, 0, stream>>>(hB, mbs, poolM, 0.2375f);
  {
    dim3 g1(1, B / 8);
    k_mlp<DM, 256, true><<<g1, 256, 0, stream>>>(poolM, DM, invM, mh1T, mol_b1, th, 256, 0);
    k_mlp<256, 112, false><<<g1, 256, 0, stream>>>(th, 256, nullptr, mh2T, mol_b2, xc, 256, 0);
  }

  // ===== PRO branch (bf16 feature rows; mean-aggr keeps noise bounded) =====
  constexpr int SHP = 9;
  constexpr int NBP = (NP + (1 << SHP) - 1) >> SHP;
  hipMemsetAsync(pbh, 0, 512 * 4, stream);
  hipMemsetAsync(poolP, 0, (size_t)B * DP2 * 4, stream);
  k_bhist<SHP><<<(EP + 4095) / 4096, 256, 0, stream>>>(p_e1, pbh, EP);
  k_scanb<<<1, 512, 0, stream>>>(pbh, pbed, pbc, NBP, EP);
  k_bin<SHP><<<(EP + 4095) / 4096, 256, 0, stream>>>(p_e0, p_e1, pbc, pbinned, EP);
  k_build<SHP><<<NBP, 256, 0, stream>>>(pbinned, pbed, pdeg, pstart, pcsr, NP);
  k_bstart<<<(NP + 255) / 256, 256, 0, stream>>>(p_batch, pbs, NP);
  k_inv<<<1, 128, 0, stream>>>(pbs, invP);
  k_cast<<<(NP * 27 + 255) / 256, 256, 0, stream>>>(pro_x, pxh, NP);

  int gb_p = (NP * 64 + 255) / 256;
  k_gatherh<<<gb_p, 256, 0, stream>>>(pxh, pstart, pdeg, pcsr, aggh, NP);
  k_sage1c<<<(NP + 63) / 64, 256, 0, stream>>>(pro_x, aggh, w1cat, bl1c, xt1h, NP);
  k_gatherh<<<gb_p, 256, 0, stream>>>(xt1h, pstart, pdeg, pcsr, aggh, NP);
  k_sage2c<8><<<B * 8, 256, 0, stream>>>(xt1h, aggh, w2cat, c2_bl, pbs, poolP);
  {
    dim3 g1(1, B / 8);
    k_mlp<DP2, 256, true><<<g1, 256, 0, stream>>>(poolP, DP2, invP, ph1T, pro_b1, th, 256, 0);
    k_mlp<256, 144, false><<<g1, 256, 0, stream>>>(th, 256, nullptr, ph2T, pro_b2, xc, 256, 112);
  }

  // ===== final MLP: xc -> 1024 relu -> 512 relu -> 1 =====
  {
    dim3 gA(4, B / 8);
    k_mlp<256, 1024, true><<<gA, 256, 0, stream>>>(xc, 256, nullptr, fc1T, fc1_b, t1, 1024, 0);
    dim3 gB(2, B / 8);
    k_mlp<1024, 512, true><<<gB, 256, 0, stream>>>(t1, 1024, nullptr, fc2T, fc2_b, t2, 512, 0);
    k_gemv1<<<B, 64, 0, stream>>>(t2, out_W, out_b, out);
  }
}

// Round 13
// 867.143 us; speedup vs baseline: 1.5987x; 1.0420x over previous
//
#include <hip/hip_runtime.h>

#define K256 __launch_bounds__(256)

constexpr int B = 128;
constexpr int NM = 100000, EM = 400000;
constexpr int NP = 200000, EP = 3200000;
constexpr int DM = 78, DPK = 54, DP2 = 108;
constexpr int XH = 32;   // pro bf16 row stride in ushort2 (128 B)
constexpr int XH4 = 16;  // pro row stride in ushort4
constexpr int MH = 48;   // mol bf16 row stride in ushort2 (192 B, 3 lines)

// ---- bf16 helpers (RTNE) ----
__device__ __forceinline__ float b2f(unsigned short u) {
  return __uint_as_float((unsigned int)u << 16);
}
__device__ __forceinline__ unsigned short f2b(float f) {
  unsigned int b = __float_as_uint(f);
  return (unsigned short)((b + 0x7fffu + ((b >> 16) & 1u)) >> 16);
}

// ---------- CSR build: bucket histogram (LDS-aggregated, no per-node atomics) ----------
template <int SH>
__global__ void K256 k_bhist(const int* __restrict__ dst, int* __restrict__ bhist, int E) {
  __shared__ int lh[512];
  int tid = threadIdx.x;
  for (int t = tid; t < 512; t += 256) lh[t] = 0;
  __syncthreads();
  int c0 = blockIdx.x * 4096;
#pragma unroll
  for (int k = 0; k < 16; k++) {
    int e = c0 + k * 256 + tid;
    if (e < E) atomicAdd(&lh[dst[e] >> SH], 1);
  }
  __syncthreads();
  for (int t = tid; t < 512; t += 256) {
    int c = lh[t];
    if (c) atomicAdd(&bhist[t], c);
  }
}

// one-block scan of bucket counts -> bed (exclusive, +total) and bcur
__global__ void k_scanb(const int* __restrict__ bhist, int* __restrict__ bed,
                        int* __restrict__ bcur, int NB, int E) {
  __shared__ int s[512];
  int tid = threadIdx.x;
  int v = (tid < NB) ? bhist[tid] : 0;
  s[tid] = v;
  __syncthreads();
  for (int off = 1; off < 512; off <<= 1) {
    int t = (tid >= off) ? s[tid - off] : 0;
    __syncthreads();
    s[tid] += t;
    __syncthreads();
  }
  int excl = s[tid] - v;
  if (tid < NB) {
    bed[tid] = excl;
    bcur[tid] = excl;
  }
  if (tid == NB - 1) bed[NB] = E;
}

// Pass A: bucket-grouped edge binning (counting-sort per 4096-edge chunk).
template <int SH>
__global__ void K256 k_bin(const int* __restrict__ src, const int* __restrict__ dst,
                           int* __restrict__ bcur, int2* __restrict__ binned, int E) {
  __shared__ int lh[512];
  __shared__ int gbase[512];
  int c0 = blockIdx.x * 4096;
  int tid = threadIdx.x;
  for (int t = tid; t < 512; t += 256) lh[t] = 0;
  __syncthreads();
  int r[16], dcache[16];
#pragma unroll
  for (int k = 0; k < 16; k++) {
    int e = c0 + k * 256 + tid;
    if (e < E) {
      int d = dst[e];
      dcache[k] = d;
      r[k] = atomicAdd(&lh[d >> SH], 1);
    }
  }
  __syncthreads();
  for (int b = tid; b < 512; b += 256) {
    int c = lh[b];
    gbase[b] = c ? atomicAdd(&bcur[b], c) : 0;
  }
  __syncthreads();
#pragma unroll
  for (int k = 0; k < 16; k++) {
    int e = c0 + k * 256 + tid;
    if (e < E) {
      int d = dcache[k];
      binned[gbase[d >> SH] + r[k]] = make_int2(src[e], d);
    }
  }
}

// Pass B (fused): per-bucket count -> LDS scan -> deg/starts write -> CSR fill.
template <int SH>
__global__ void K256 k_build(const int2* __restrict__ binned, const int* __restrict__ bed,
                             int* __restrict__ deg, int* __restrict__ starts,
                             int* __restrict__ csr, int N) {
  constexpr int NN = 1 << SH;
  constexpr int P = NN / 256;
  __shared__ int lcnt[NN];
  __shared__ int lpair[256];
  int b = blockIdx.x, base = b << SH, tid = threadIdx.x;
  int nn = min(N - base, NN);
  for (int t = tid; t < NN; t += 256) lcnt[t] = 0;
  __syncthreads();
  int e0 = bed[b], e1 = bed[b + 1];
  for (int e = e0 + tid; e < e1; e += 256) atomicAdd(&lcnt[binned[e].y - base], 1);
  __syncthreads();
  int loc[P];
  int psum = 0;
#pragma unroll
  for (int p = 0; p < P; p++) {
    loc[p] = lcnt[tid * P + p];
    psum += loc[p];
  }
  lpair[tid] = psum;
  __syncthreads();
  for (int off = 1; off < 256; off <<= 1) {
    int t = (tid >= off) ? lpair[tid - off] : 0;
    __syncthreads();
    lpair[tid] += t;
    __syncthreads();
  }
  int run = lpair[tid] - psum;
  __syncthreads();  // done reading lcnt as counts; reuse as cursors
#pragma unroll
  for (int p = 0; p < P; p++) {
    int i = tid * P + p;
    int st = e0 + run;
    if (i < nn) {
      deg[base + i] = loc[p];
      starts[base + i] = st;
    }
    lcnt[i] = st;
    run += loc[p];
  }
  __syncthreads();
  for (int e = e0 + tid; e < e1; e += 256) {
    int2 sd = binned[e];
    int p = atomicAdd(&lcnt[sd.y - base], 1);
    csr[p] = sd.x;
  }
}

// ---------- batch segment starts (batch is sorted) ----------
__global__ void K256 k_bstart(const int* __restrict__ batch, int* __restrict__ bstart, int N) {
  int i = blockIdx.x * 256 + threadIdx.x;
  if (i < N) {
    int b = batch[i];
    int pb = (i == 0) ? -1 : batch[i - 1];
    for (int bb = pb + 1; bb <= b; bb++) bstart[bb] = i;
    if (i == N - 1)
      for (int bb = b + 1; bb <= B; bb++) bstart[bb] = N;
  }
}

__global__ void k_inv(const int* __restrict__ bstart, float* __restrict__ inv) {
  int b = threadIdx.x;
  if (b < B) inv[b] = 1.f / fmaxf((float)(bstart[b + 1] - bstart[b]), 1.f);
}

// ---------- tiled transpose ----------
__global__ void K256 k_transT(const float* __restrict__ in, float* __restrict__ out, int R,
                              int C) {
  __shared__ float t[32][33];
  int cb = blockIdx.x * 32, rb = blockIdx.y * 32;
  int tx = threadIdx.x & 31, ty = threadIdx.x >> 5;
  for (int i = ty; i < 32; i += 8) {
    int r = rb + i, c = cb + tx;
    if (r < R && c < C) t[i][tx] = in[(size_t)r * C + c];
  }
  __syncthreads();
  for (int i = ty; i < 32; i += 8) {
    int c = cb + i, r = rb + tx;
    if (r < R && c < C) out[(size_t)c * R + r] = t[tx][i];
  }
}

// ---------- weight prep: cat-form transposed weights ----------
__global__ void K256 k_prepw(const float* __restrict__ c1Wl, const float* __restrict__ c1Wr,
                             const float* __restrict__ c1bl, const float* __restrict__ c2Wl,
                             const float* __restrict__ c2Wr, float* __restrict__ w1cat,
                             float* __restrict__ bl1c, float* __restrict__ w2cat) {
  int i = blockIdx.x * 256 + threadIdx.x;
  if (i < 108 * 56) {
    int k = i / 56, o = i - k * 56;
    w1cat[i] = (o < 54) ? ((k < 54) ? c1Wl[o * 54 + k] : c1Wr[o * 54 + (k - 54)]) : 0.f;
  }
  if (i < 108 * 108) {
    int k = i / 108, o = i - k * 108;
    w2cat[i] = (k < 54) ? c2Wl[o * 54 + k] : c2Wr[o * 54 + (k - 54)];
  }
  if (i < 56) bl1c[i] = (i < 54) ? c1bl[i] : 0.f;
}

// ---------- cast f32 rows -> bf16 rows ----------
template <int DF2, int XHD>
__global__ void K256 k_castg(const float* __restrict__ x, int sstride,
                             ushort2* __restrict__ xh, int N) {
  int t = blockIdx.x * 256 + threadIdx.x;
  if (t < N * DF2) {
    int n = t / DF2, j = t - n * DF2;
    float2 v = *(const float2*)(x + (size_t)n * sstride + 2 * j);
    xh[(size_t)n * XHD + j] = make_ushort2(f2b(v.x), f2b(v.y));
  }
}

// ---------- pro bf16 gather: 4 edges/wave, ushort4 lanes (14 of 16), 8-deep ILP ----------
__global__ void K256 k_gatherh(const ushort4* __restrict__ xh4, const int* __restrict__ starts,
                               const int* __restrict__ deg, const int* __restrict__ csr,
                               ushort4* __restrict__ outh4, int N) {
  int wid = (blockIdx.x * 256 + threadIdx.x) >> 6;
  int lane = threadIdx.x & 63;
  if (wid >= N) return;
  int s = starts[wid], d = deg[wid];
  const int* cp = csr + s;
  int quarter = lane >> 4, sl = lane & 15;
  bool act = sl < 14;
  float a0 = 0.f, a1 = 0.f, a2 = 0.f, a3 = 0.f;
  float b0 = 0.f, b1 = 0.f, b2 = 0.f, b3 = 0.f;
  int j = 0;
  for (; j + 8 <= d; j += 8) {
    if (act) {
      ushort4 v = xh4[(size_t)cp[j + quarter] * XH4 + sl];
      ushort4 w = xh4[(size_t)cp[j + 4 + quarter] * XH4 + sl];
      a0 += b2f(v.x);
      a1 += b2f(v.y);
      a2 += b2f(v.z);
      a3 += b2f(v.w);
      b0 += b2f(w.x);
      b1 += b2f(w.y);
      b2 += b2f(w.z);
      b3 += b2f(w.w);
    }
  }
  for (; j + 4 <= d; j += 4) {
    if (act) {
      ushort4 v = xh4[(size_t)cp[j + quarter] * XH4 + sl];
      a0 += b2f(v.x);
      a1 += b2f(v.y);
      a2 += b2f(v.z);
      a3 += b2f(v.w);
    }
  }
  int r = d - j;
  if (quarter < r && act) {
    ushort4 v = xh4[(size_t)cp[j + quarter] * XH4 + sl];
    a0 += b2f(v.x);
    a1 += b2f(v.y);
    a2 += b2f(v.z);
    a3 += b2f(v.w);
  }
  a0 += b0;
  a1 += b1;
  a2 += b2;
  a3 += b3;
  a0 += __shfl_xor(a0, 16, 64);
  a1 += __shfl_xor(a1, 16, 64);
  a2 += __shfl_xor(a2, 16, 64);
  a3 += __shfl_xor(a3, 16, 64);
  a0 += __shfl_xor(a0, 32, 64);
  a1 += __shfl_xor(a1, 32, 64);
  a2 += __shfl_xor(a2, 32, 64);
  a3 += __shfl_xor(a3, 32, 64);
  if (lane < 14) {
    float inv = 1.f / fmaxf((float)d, 1.f);
    outh4[(size_t)wid * XH4 + lane] =
        make_ushort4(f2b(a0 * inv), f2b(a1 * inv), f2b(a2 * inv), f2b(a3 * inv));
  }
}

// ---------- mol bf16 gather (sum): wave per node, 39 ushort2 lanes, 4-deep ILP ----------
__global__ void K256 k_gatherm(const ushort2* __restrict__ xh, const int* __restrict__ starts,
                               const int* __restrict__ deg, const int* __restrict__ csr,
                               ushort2* __restrict__ outh, int N) {
  int wid = (blockIdx.x * 256 + threadIdx.x) >> 6;
  int lane = threadIdx.x & 63;
  if (wid >= N) return;
  int s = starts[wid], d = deg[wid];
  const int* cp = csr + s;
  bool act = lane < 39;
  float ax = 0.f, ay = 0.f, bx = 0.f, by = 0.f;
  int j = 0;
  for (; j + 4 <= d; j += 4) {
    if (act) {
      ushort2 v0 = xh[(size_t)cp[j] * MH + lane];
      ushort2 v1 = xh[(size_t)cp[j + 1] * MH + lane];
      ushort2 v2 = xh[(size_t)cp[j + 2] * MH + lane];
      ushort2 v3 = xh[(size_t)cp[j + 3] * MH + lane];
      ax += b2f(v0.x) + b2f(v2.x);
      ay += b2f(v0.y) + b2f(v2.y);
      bx += b2f(v1.x) + b2f(v3.x);
      by += b2f(v1.y) + b2f(v3.y);
    }
  }
  for (; j < d; j++) {
    if (act) {
      ushort2 v = xh[(size_t)cp[j] * MH + lane];
      ax += b2f(v.x);
      ay += b2f(v.y);
    }
  }
  ax += bx;
  ay += by;
  if (act) outh[(size_t)wid * MH + lane] = make_ushort2(f2b(ax), f2b(ay));
}

// ---------- mol segmented pooling over bf16 rows, split + ILP-4 ----------
template <int SPLIT>
__global__ void K256 k_pool_segh(const ushort2* __restrict__ xh, const int* __restrict__ bstart,
                                 float* __restrict__ pooled, float coef) {
  constexpr int NPB = 6;  // 39 u2 * 6 = 234 threads
  __shared__ float sp[NPB * DM];
  int b = blockIdx.x / SPLIT;
  int sidx = blockIdx.x - b * SPLIT;
  int tid = threadIdx.x;
  int r0 = bstart[b], r1 = bstart[b + 1];
  int len = r1 - r0;
  int per = (len + SPLIT - 1) / SPLIT;
  int s0 = r0 + sidx * per;
  int s1 = min(r1, s0 + per);
  if (tid < 39 * NPB) {
    int ioff = tid / 39, j = tid - ioff * 39;
    float a0x = 0.f, a0y = 0.f, a1x = 0.f, a1y = 0.f;
    int i = s0 + ioff;
    for (; i + 3 * NPB < s1; i += 4 * NPB) {
      ushort2 v0 = xh[(size_t)i * MH + j];
      ushort2 v1 = xh[(size_t)(i + NPB) * MH + j];
      ushort2 v2 = xh[(size_t)(i + 2 * NPB) * MH + j];
      ushort2 v3 = xh[(size_t)(i + 3 * NPB) * MH + j];
      a0x += b2f(v0.x) + b2f(v2.x);
      a0y += b2f(v0.y) + b2f(v2.y);
      a1x += b2f(v1.x) + b2f(v3.x);
      a1y += b2f(v1.y) + b2f(v3.y);
    }
    for (; i < s1; i += NPB) {
      ushort2 v = xh[(size_t)i * MH + j];
      a0x += b2f(v.x);
      a0y += b2f(v.y);
    }
    sp[ioff * DM + 2 * j] = a0x + a1x;
    sp[ioff * DM + 2 * j + 1] = a0y + a1y;
  }
  __syncthreads();
  if (tid < DM) {
    float s = 0.f;
#pragma unroll
    for (int g = 0; g < NPB; g++) s += sp[g * DM + tid];
    s *= coef;
    if (s != 0.f) atomicAdd(&pooled[b * DM + tid], s);
  }
}

// ---------- SAGE conv1 cat-form: 64-node tile, 4 waves x 14 outputs; bf16 agg in, bf16 out ----------
__global__ void __launch_bounds__(256, 4) k_sage1c(
    const float* __restrict__ x, const ushort2* __restrict__ aggh,
    const float* __restrict__ wcat, const float* __restrict__ blc,
    ushort2* __restrict__ outh, int N) {
  __shared__ float scat[64 * 109];
  int base = blockIdx.x * 64;
  int nn = min(N - base, 64);
  int tid = threadIdx.x;
  for (int t = tid; t < nn * 27; t += 256) {
    int n = t / 27, j = t - n * 27;
    ushort2 va = aggh[(size_t)(base + n) * XH + j];
    float2 vx = *(const float2*)(x + (size_t)(base + n) * 54 + 2 * j);
    float* sr = scat + n * 109;
    sr[2 * j] = b2f(va.x);
    sr[2 * j + 1] = b2f(va.y);
    sr[54 + 2 * j] = vx.x;
    sr[54 + 2 * j + 1] = vx.y;
  }
  __syncthreads();
  int w = tid >> 6, lane = tid & 63;
  int obase = __builtin_amdgcn_readfirstlane(w * 14);
  if (lane >= nn) return;
  float acc[14];
#pragma unroll
  for (int o = 0; o < 14; o++) acc[o] = blc[obase + o];
  const float* rs = scat + lane * 109;
#pragma unroll 2
  for (int k = 0; k < 108; k++) {
    float v = rs[k];
    const float* wr = wcat + k * 56 + obase;
#pragma unroll
    for (int o = 0; o < 14; o++) acc[o] += v * wr[o];
  }
  ushort2* op = outh + (size_t)(base + lane) * XH + (obase >> 1);
#pragma unroll
  for (int o = 0; o < 7; o++)
    op[o] = make_ushort2(f2b(fmaxf(acc[2 * o], 0.f)), f2b(fmaxf(acc[2 * o + 1], 0.f)));
}

// ---------- conv2 + pool cat-form: 64-node tile, 4 waves x 27 outputs; bf16 inputs ----------
template <int SPLIT>
__global__ void __launch_bounds__(256, 4) k_sage2c(
    const ushort2* __restrict__ xt1h, const ushort2* __restrict__ aggh,
    const float* __restrict__ wcat, const float* __restrict__ bl,
    const int* __restrict__ bstart, float* __restrict__ pooled) {
  __shared__ float scat[64 * 109];
  int b = blockIdx.x / SPLIT;
  int sidx = blockIdx.x - b * SPLIT;
  int tid = threadIdx.x;
  int w = tid >> 6, lane = tid & 63;
  int obase = __builtin_amdgcn_readfirstlane(w * 27);
  int r0 = bstart[b], r1 = bstart[b + 1];
  int len = r1 - r0;
  int per = (len + SPLIT - 1) / SPLIT;
  int s0 = r0 + sidx * per;
  int s1 = min(r1, s0 + per);
  float pool[27];
#pragma unroll
  for (int o = 0; o < 27; o++) pool[o] = 0.f;
  for (int tb = s0; tb < s1; tb += 64) {
    int nn = min(s1 - tb, 64);
    __syncthreads();
    for (int t = tid; t < nn * 27; t += 256) {
      int n = t / 27, j = t - n * 27;
      ushort2 va = aggh[(size_t)(tb + n) * XH + j];
      ushort2 vx = xt1h[(size_t)(tb + n) * XH + j];
      float* sr = scat + n * 109;
      sr[2 * j] = b2f(va.x);
      sr[2 * j + 1] = b2f(va.y);
      sr[54 + 2 * j] = b2f(vx.x);
      sr[54 + 2 * j + 1] = b2f(vx.y);
    }
    __syncthreads();
    if (lane < nn) {
      float acc[27];
#pragma unroll
      for (int o = 0; o < 27; o++) acc[o] = bl[obase + o];
      const float* rs = scat + lane * 109;
#pragma unroll 2
      for (int k = 0; k < 108; k++) {
        float v = rs[k];
        const float* wr = wcat + k * 108 + obase;
#pragma unroll
        for (int o = 0; o < 27; o++) acc[o] += v * wr[o];
      }
#pragma unroll
      for (int o = 0; o < 27; o++) pool[o] += fmaxf(acc[o], 0.f);
    }
  }
#pragma unroll
  for (int o = 0; o < 27; o++) {
#pragma unroll
    for (int off = 1; off < 64; off <<= 1) pool[o] += __shfl_xor(pool[o], off, 64);
  }
  if (lane == 0) {
    float* pb = pooled + b * DP2 + obase;
#pragma unroll
    for (int o = 0; o < 27; o++)
      if (pool[o] != 0.f) atomicAdd(&pb[o], pool[o]);
  }
}

// ---------- tiny GEMM: Y[128][DOUT](+ycol0) = act(X[128][DIN] (*rs) @ WT + b) ----------
template <int DIN, int DOUT, bool RELU>
__global__ void K256 k_mlp(const float* __restrict__ X, int xstride,
                           const float* __restrict__ rs, const float* __restrict__ WT,
                           const float* __restrict__ bias, float* __restrict__ Y,
                           int ystride, int ycol0) {
  constexpr int BT = 8;
  __shared__ float Xs[BT][DIN];
  int tid = threadIdx.x;
  int ob = blockIdx.x * 256 + tid;
  int bb = blockIdx.y * BT;
  for (int t = tid; t < BT * DIN; t += 256) {
    int i = t / DIN, k = t - i * DIN;
    float v = X[(size_t)(bb + i) * xstride + k];
    if (rs) v *= rs[bb + i];
    Xs[i][k] = v;
  }
  __syncthreads();
  int o = (ob < DOUT) ? ob : (DOUT - 1);
  float bv = bias[o];
  float acc[BT];
#pragma unroll
  for (int i = 0; i < BT; i++) acc[i] = bv;
#pragma unroll 4
  for (int k = 0; k < DIN; k++) {
    float w = WT[(size_t)k * DOUT + o];
#pragma unroll
    for (int i = 0; i < BT; i++) acc[i] += Xs[i][k] * w;
  }
  if (ob < DOUT) {
#pragma unroll
    for (int i = 0; i < BT; i++) {
      float v = RELU ? fmaxf(acc[i], 0.f) : acc[i];
      Y[(size_t)(bb + i) * ystride + ycol0 + ob] = v;
    }
  }
}

// ---------- final 512 -> 1 GEMV ----------
__global__ void __launch_bounds__(64) k_gemv1(const float* __restrict__ t2,
                                              const float* __restrict__ W3,
                                              const float* __restrict__ b3,
                                              float* __restrict__ out) {
  int b = blockIdx.x, lane = threadIdx.x;
  float a = 0.f;
  const float* row = t2 + (size_t)b * 512;
#pragma unroll 2
  for (int k = lane; k < 512; k += 64) a += row[k] * W3[k];
#pragma unroll
  for (int off = 32; off > 0; off >>= 1) a += __shfl_down(a, off, 64);
  if (lane == 0) out[b] = a + b3[0];
}

__global__ void k_report(float* out, float v, int n) {
  int i = blockIdx.x * 256 + threadIdx.x;
  if (i < n) out[i] = v;
}

extern "C" void kernel_launch(void* const* d_in, const int* in_sizes, int n_in,
                              void* d_out, int out_size, void* d_ws, size_t ws_size,
                              hipStream_t stream) {
  (void)in_sizes; (void)n_in;
  const float* mol_x = (const float*)d_in[0];
  const int* m_ei = (const int*)d_in[1];
  const int* m_batch = (const int*)d_in[2];
  const float* pro_x = (const float*)d_in[3];
  const int* p_ei = (const int*)d_in[4];
  const int* p_batch = (const int*)d_in[5];
  const float* mol_W1 = (const float*)d_in[6];
  const float* mol_b1 = (const float*)d_in[7];
  const float* mol_W2 = (const float*)d_in[8];
  const float* mol_b2 = (const float*)d_in[9];
  const float* c1_Wl = (const float*)d_in[10];
  const float* c1_bl = (const float*)d_in[11];
  const float* c1_Wr = (const float*)d_in[12];
  const float* c2_Wl = (const float*)d_in[13];
  const float* c2_bl = (const float*)d_in[14];
  const float* c2_Wr = (const float*)d_in[15];
  const float* pro_W1 = (const float*)d_in[16];
  const float* pro_b1 = (const float*)d_in[17];
  const float* pro_W2 = (const float*)d_in[18];
  const float* pro_b2 = (const float*)d_in[19];
  const float* fc1_W = (const float*)d_in[20];
  const float* fc1_b = (const float*)d_in[21];
  const float* fc2_W = (const float*)d_in[22];
  const float* fc2_b = (const float*)d_in[23];
  const float* out_W = (const float*)d_in[24];
  const float* out_b = (const float*)d_in[25];
  float* out = (float*)d_out;
  char* ws = (char*)d_ws;

  const int* m_row = m_ei;       // dst
  const int* m_col = m_ei + EM;  // src
  const int* p_e0 = p_ei;        // src
  const int* p_e1 = p_ei + EP;   // dst

  auto al = [](size_t x) { return (x + 255) & ~(size_t)255; };

  size_t o = 0;
  size_t o_pdeg = o;   o += al((size_t)NP * 4);
  size_t o_pstart = o; o += al((size_t)NP * 4);
  size_t o_pcsr = o;   o += al((size_t)EP * 4);
  size_t o_aggh = o;   o += al((size_t)NP * XH * 4);  // also pro binned (25.6MB)
  size_t o_xt1h = o;   o += al((size_t)NP * XH * 4);
  size_t o_pxh = o;    o += al((size_t)NP * XH * 4);
  size_t pro_end = o;

  o = 0;
  size_t o_mdeg = o;   o += al((size_t)NM * 4);
  size_t o_mstart = o; o += al((size_t)NM * 4);
  size_t o_mcsr = o;   o += al((size_t)EM * 4);
  size_t o_mxh = o;    o += al((size_t)NM * MH * 4);
  size_t o_hAh = o;    o += al((size_t)NM * MH * 4);  // also mol binned (3.2MB)
  size_t o_hBh = o;    o += al((size_t)NM * MH * 4);
  size_t mol_end = o;

  size_t tail = al(pro_end > mol_end ? pro_end : mol_end);
  size_t o_poolM = tail; tail += al((size_t)B * DM * 4);
  size_t o_poolP = tail; tail += al((size_t)B * DP2 * 4);
  size_t o_mbs = tail;   tail += al((size_t)(B + 1) * 4);
  size_t o_pbs = tail;   tail += al((size_t)(B + 1) * 4);
  size_t o_w1c = tail;   tail += al((size_t)108 * 56 * 4);
  size_t o_bl1 = tail;   tail += al(56 * 4);
  size_t o_w2c = tail;   tail += al((size_t)108 * 108 * 4);
  size_t o_mbc = tail;   tail += al(512 * 4);
  size_t o_pbc = tail;   tail += al(512 * 4);
  size_t o_mbh = tail;   tail += al(512 * 4);
  size_t o_pbh = tail;   tail += al(512 * 4);
  size_t o_mbed = tail;  tail += al(513 * 4);
  size_t o_pbed = tail;  tail += al(513 * 4);
  // MLP machinery
  size_t o_mh1T = tail;  tail += al((size_t)DM * 256 * 4);
  size_t o_mh2T = tail;  tail += al((size_t)256 * 112 * 4);
  size_t o_ph1T = tail;  tail += al((size_t)DP2 * 256 * 4);
  size_t o_ph2T = tail;  tail += al((size_t)256 * 144 * 4);
  size_t o_fc1T = tail;  tail += al((size_t)256 * 1024 * 4);
  size_t o_fc2T = tail;  tail += al((size_t)1024 * 512 * 4);
  size_t o_xc = tail;    tail += al((size_t)B * 256 * 4);
  size_t o_t1 = tail;    tail += al((size_t)B * 1024 * 4);
  size_t o_t2 = tail;    tail += al((size_t)B * 512 * 4);
  size_t o_th = tail;    tail += al((size_t)B * 256 * 4);
  size_t o_invM = tail;  tail += al(B * 4);
  size_t o_invP = tail;  tail += al(B * 4);

  if (ws_size < tail) {
    k_report<<<1, 256, 0, stream>>>(out, (float)(ws_size >> 20), out_size);
    return;
  }

  int* mdeg = (int*)(ws + o_mdeg);
  int* mstart = (int*)(ws + o_mstart);
  int* mcsr = (int*)(ws + o_mcsr);
  ushort2* mxh = (ushort2*)(ws + o_mxh);
  ushort2* hAh = (ushort2*)(ws + o_hAh);
  ushort2* hBh = (ushort2*)(ws + o_hBh);
  int* pdeg = (int*)(ws + o_pdeg);
  int* pstart = (int*)(ws + o_pstart);
  int* pcsr = (int*)(ws + o_pcsr);
  ushort2* aggh = (ushort2*)(ws + o_aggh);
  ushort2* xt1h = (ushort2*)(ws + o_xt1h);
  ushort2* pxh = (ushort2*)(ws + o_pxh);
  float* poolM = (float*)(ws + o_poolM);
  float* poolP = (float*)(ws + o_poolP);
  int* mbs = (int*)(ws + o_mbs);
  int* pbs = (int*)(ws + o_pbs);
  float* w1cat = (float*)(ws + o_w1c);
  float* bl1c = (float*)(ws + o_bl1);
  float* w2cat = (float*)(ws + o_w2c);
  int* mbc = (int*)(ws + o_mbc);
  int* pbc = (int*)(ws + o_pbc);
  int* mbh = (int*)(ws + o_mbh);
  int* pbh = (int*)(ws + o_pbh);
  int* mbed = (int*)(ws + o_mbed);
  int* pbed = (int*)(ws + o_pbed);
  float* mh1T = (float*)(ws + o_mh1T);
  float* mh2T = (float*)(ws + o_mh2T);
  float* ph1T = (float*)(ws + o_ph1T);
  float* ph2T = (float*)(ws + o_ph2T);
  float* fc1T = (float*)(ws + o_fc1T);
  float* fc2T = (float*)(ws + o_fc2T);
  float* xc = (float*)(ws + o_xc);
  float* t1 = (float*)(ws + o_t1);
  float* t2 = (float*)(ws + o_t2);
  float* th = (float*)(ws + o_th);
  float* invM = (float*)(ws + o_invM);
  float* invP = (float*)(ws + o_invP);
  int2* mbinned = (int2*)hAh;   // consumed by k_build before hAh written
  int2* pbinned = (int2*)aggh;  // consumed by k_build before aggh written

  // weight prep
  k_prepw<<<(108 * 108 + 255) / 256, 256, 0, stream>>>(c1_Wl, c1_Wr, c1_bl, c2_Wl, c2_Wr,
                                                       w1cat, bl1c, w2cat);
  {
    auto tg = [](int R, int C) { return dim3((C + 31) / 32, (R + 31) / 32); };
    k_transT<<<tg(256, DM), 256, 0, stream>>>(mol_W1, mh1T, 256, DM);
    k_transT<<<tg(112, 256), 256, 0, stream>>>(mol_W2, mh2T, 112, 256);
    k_transT<<<tg(256, DP2), 256, 0, stream>>>(pro_W1, ph1T, 256, DP2);
    k_transT<<<tg(144, 256), 256, 0, stream>>>(pro_W2, ph2T, 144, 256);
    k_transT<<<tg(1024, 256), 256, 0, stream>>>(fc1_W, fc1T, 1024, 256);
    k_transT<<<tg(512, 1024), 256, 0, stream>>>(fc2_W, fc2T, 512, 1024);
  }

  // ===== MOL branch (bf16 rows; APPNP sums accumulate in f32, stored bf16/hop) =====
  constexpr int SHM = 8;
  constexpr int NBM = (NM + (1 << SHM) - 1) >> SHM;
  hipMemsetAsync(mbh, 0, 512 * 4, stream);
  hipMemsetAsync(poolM, 0, (size_t)B * DM * 4, stream);
  k_bhist<SHM><<<(EM + 4095) / 4096, 256, 0, stream>>>(m_row, mbh, EM);
  k_scanb<<<1, 512, 0, stream>>>(mbh, mbed, mbc, NBM, EM);
  k_bin<SHM><<<(EM + 4095) / 4096, 256, 0, stream>>>(m_col, m_row, mbc, mbinned, EM);
  k_build<SHM><<<NBM, 256, 0, stream>>>(mbinned, mbed, mdeg, mstart, mcsr, NM);
  k_bstart<<<(NM + 255) / 256, 256, 0, stream>>>(m_batch, mbs, NM);
  k_inv<<<1, 128, 0, stream>>>(mbs, invM);
  k_castg<39, MH><<<(NM * 39 + 255) / 256, 256, 0, stream>>>(mol_x, DM, mxh, NM);

  int gb_m = (NM * 64 + 255) / 256;
  k_pool_segh<8><<<B * 8, 256, 0, stream>>>(mxh, mbs, poolM, 0.05f);
  k_gatherm<<<gb_m, 256, 0, stream>>>(mxh, mstart, mdeg, mcsr, hAh, NM);
  k_pool_segh<8><<<B * 8, 256, 0, stream>>>(hAh, mbs, poolM, 0.2375f);
  k_gatherm<<<gb_m, 256, 0, stream>>>(hAh, mstart, mdeg, mcsr, hBh, NM);
  k_pool_segh<8><<<B * 8, 256, 0, stream>>>(hBh, mbs, poolM, 0.2375f);
  k_gatherm<<<gb_m, 256, 0, stream>>>(hBh, mstart, mdeg, mcsr, hAh, NM);
  k_pool_segh<8><<<B * 8, 256, 0, stream>>>(hAh, mbs, poolM, 0.2375f);
  k_gatherm<<<gb_m, 256, 0, stream>>>(hAh, mstart, mdeg, mcsr, hBh, NM);
  k_pool_segh<8><<<B * 8, 256, 0, stream>>>(hBh, mbs, poolM, 0.2375f);
  {
    dim3 g1(1, B / 8);
    k_mlp<DM, 256, true><<<g1, 256, 0, stream>>>(poolM, DM, invM, mh1T, mol_b1, th, 256, 0);
    k_mlp<256, 112, false><<<g1, 256, 0, stream>>>(th, 256, nullptr, mh2T, mol_b2, xc, 256, 0);
  }

  // ===== PRO branch (bf16 rows) =====
  constexpr int SHP = 9;
  constexpr int NBP = (NP + (1 << SHP) - 1) >> SHP;
  hipMemsetAsync(pbh, 0, 512 * 4, stream);
  hipMemsetAsync(poolP, 0, (size_t)B * DP2 * 4, stream);
  k_bhist<SHP><<<(EP + 4095) / 4096, 256, 0, stream>>>(p_e1, pbh, EP);
  k_scanb<<<1, 512, 0, stream>>>(pbh, pbed, pbc, NBP, EP);
  k_bin<SHP><<<(EP + 4095) / 4096, 256, 0, stream>>>(p_e0, p_e1, pbc, pbinned, EP);
  k_build<SHP><<<NBP, 256, 0, stream>>>(pbinned, pbed, pdeg, pstart, pcsr, NP);
  k_bstart<<<(NP + 255) / 256, 256, 0, stream>>>(p_batch, pbs, NP);
  k_inv<<<1, 128, 0, stream>>>(pbs, invP);
  k_castg<27, XH><<<(NP * 27 + 255) / 256, 256, 0, stream>>>(pro_x, DPK, pxh, NP);

  int gb_p = (NP * 64 + 255) / 256;
  k_gatherh<<<gb_p, 256, 0, stream>>>((const ushort4*)pxh, pstart, pdeg, pcsr,
                                      (ushort4*)aggh, NP);
  k_sage1c<<<(NP + 63) / 64, 256, 0, stream>>>(pro_x, aggh, w1cat, bl1c, xt1h, NP);
  k_gatherh<<<gb_p, 256, 0, stream>>>((const ushort4*)xt1h, pstart, pdeg, pcsr,
                                      (ushort4*)aggh, NP);
  k_sage2c<8><<<B * 8, 256, 0, stream>>>(xt1h, aggh, w2cat, c2_bl, pbs, poolP);
  {
    dim3 g1(1, B / 8);
    k_mlp<DP2, 256, true><<<g1, 256, 0, stream>>>(poolP, DP2, invP, ph1T, pro_b1, th, 256, 0);
    k_mlp<256, 144, false><<<g1, 256, 0, stream>>>(th, 256, nullptr, ph2T, pro_b2, xc, 256, 112);
  }

  // ===== final MLP =====
  {
    dim3 gA(4, B / 8);
    k_mlp<256, 1024, true><<<gA, 256, 0, stream>>>(xc, 256, nullptr, fc1T, fc1_b, t1, 1024, 0);
    dim3 gB(2, B / 8);
    k_mlp<1024, 512, true><<<gB, 256, 0, stream>>>(t1, 1024, nullptr, fc2T, fc2_b, t2, 512, 0);
    k_gemv1<<<B, 64, 0, stream>>>(t2, out_W, out_b, out);
  }
}